// Round 5
// baseline (1999.552 us; speedup 1.0000x reference)
//
#include <hip/hip_runtime.h>
#include <cmath>

typedef unsigned int u32;
typedef unsigned long long u64;

#define NCAND 4507
#define WORDS 71              // ceil(4507/64)
#define ROWS_AL (WORDS * 64)  // 4544
#define TOTS 159882           // total scores across levels

__constant__ int c_W[5]      = {200, 100, 50, 25, 13};
__constant__ int c_stride[5] = {4, 8, 16, 32, 61};
__constant__ int c_Nl[5]     = {120000, 30000, 7500, 1875, 507};
__constant__ int c_soff[5]   = {0, 120000, 150000, 157500, 159375};
__constant__ int c_k[5]      = {1000, 1000, 1000, 1000, 507};

// unified conv grid: tiles per level (8x8 px tiles): 625,169,49,16,4
__constant__ int cv_boff[6]  = {0, 625, 794, 843, 859, 863};

struct DecParams { float b[5][3][4]; };
struct FeatPtrs { const float* p[5]; };

__device__ __forceinline__ u32 flipf(float f) {
    u32 u = __float_as_uint(f);
    return (u & 0x80000000u) ? ~u : (u | 0x80000000u);
}

// ---------------- workspace layout ----------------
constexpr size_t AL(size_t x) { return (x + 255) & ~(size_t)255; }
constexpr size_t OFF_WT     = 0;                                   // 589824 f
constexpr size_t OFF_HEADW  = AL(OFF_WT + 589824 * 4);             // 15*256 f
constexpr size_t OFF_HEADB  = AL(OFF_HEADW + 3840 * 4);            // 15 f
constexpr size_t OFF_SCORES = AL(OFF_HEADB + 64);                  // TOTS f
constexpr size_t OFF_DELTAS = AL(OFF_SCORES + (size_t)TOTS * 4);   // TOTS*4 f
constexpr size_t OFF_KEY    = AL(OFF_DELTAS + (size_t)TOTS * 16);  // NCAND u64
constexpr size_t OFF_SBOX   = AL(OFF_KEY + (size_t)NCAND * 8);     // NCAND*4 f
constexpr size_t OFF_SOB    = AL(OFF_SBOX + (size_t)NCAND * 16);   // NCAND*4 f
constexpr size_t OFF_SVAL   = AL(OFF_SOB + (size_t)NCAND * 16);    // NCAND u32
constexpr size_t OFF_MASK   = AL(OFF_SVAL + (size_t)NCAND * 4);    // ROWS_AL*WORDS u64
constexpr size_t OFF_KEEP   = AL(OFF_MASK + (size_t)ROWS_AL * WORDS * 8); // WORDS u64

// ---------------- kernel 1: weight prep ----------------
// wT[ci][ky][kx][co]  from conv_w[co][ci][ky][kx]; combined head weights/bias.
__global__ __launch_bounds__(256) void k_prep(
    const float* __restrict__ cw, const float* __restrict__ clsw,
    const float* __restrict__ clsb, const float* __restrict__ bw,
    const float* __restrict__ bb, float* __restrict__ wT,
    float* __restrict__ headw, float* __restrict__ headb) {
    int i = blockIdx.x * 256 + threadIdx.x;
    if (i < 589824) {
        int co = i & 255, r = i >> 8;
        int kx = r % 3, ky = (r / 3) % 3, ci = r / 9;
        wT[i] = cw[(((co << 8) + ci) * 3 + ky) * 3 + kx];
    }
    if (i < 3840) {
        int h = i >> 8, ci = i & 255;
        headw[i] = (h < 3) ? clsw[h * 256 + ci] : bw[(h - 3) * 256 + ci];
    }
    if (i < 15) headb[i] = (i < 3) ? clsb[i] : bb[i - 3];
}

// ---------------- kernel 2: fused conv3x3+ReLU + 1x1 heads, ALL LEVELS ----------------
// Block: 256 threads -> 8x8 pixel tile, all 256 output channels.
// Thread (cg,pg): 8 co x 8 px register micro-tile.
// Double-buffered K-chunks (2 input channels each): prefetch next chunk's
// weights (9 float2/thread) + patch (1 float, tid<200) into REGISTERS during
// compute; one barrier per chunk. LDS = 2 x (200 patch + 8 pad + 4608 w) =
// 9632 f = 38.5 KB -> 4 blocks/CU by LDS. Accumulation order is bit-identical
// to the non-buffered chunk-4 version (ci ascending 0..255).
// NOTE: no min-waves arg on __launch_bounds__ — (256,4) capped VGPR at 64 and
// (256,3) at 84 (cap ~= 512/(2N)), both spilling GBs to scratch (r2/r3).
__global__ __launch_bounds__(256) void k_conv(
    FeatPtrs fp, const float* __restrict__ wT,
    const float* __restrict__ convb, const float* __restrict__ headw,
    const float* __restrict__ headb, float* __restrict__ scores,
    float* __restrict__ deltas) {
    __shared__ float sm[9632];  // 2 bufs @ 0/4816: [patch 200][pad 8][w 4608]; head: part[32][196]
    const int tid = threadIdx.x;
    const int cg = tid >> 3, pg = tid & 7, co0 = cg << 3;

    // level lookup
    const int bid = blockIdx.x;
    int l = 0;
#pragma unroll
    for (int q = 1; q < 5; q++) if (bid >= cv_boff[q]) l = q;
    const int H = c_W[l], W = H;
    const int soff = c_soff[l];
    const float* __restrict__ in = fp.p[l];
    const int t = bid - cv_boff[l];
    const int tilesx = (W + 7) >> 3;
    const int tx = t % tilesx, ty = t / tilesx;
    const int x0 = tx * 8, y0 = ty * 8;
    const int HW = H * W;

    // this thread's fixed patch-staging slot (tid<200): [ci 2][py 10][px 10]
    const int p_ci = tid / 100, p_rr = tid - p_ci * 100;
    const int p_py = p_rr / 10, p_px = p_rr - p_py * 10;
    const int p_gy = y0 - 1 + p_py, p_gx = x0 - 1 + p_px;
    const bool p_ok = (tid < 200) && (p_gy >= 0) && (p_gy < H) && (p_gx >= 0) && (p_gx < W);
    const int p_goff = p_ok ? (p_gy * W + p_gx) : 0;

    float acc[8][8];
#pragma unroll
    for (int r = 0; r < 8; r++)
#pragma unroll
        for (int c = 0; c < 8; c++) acc[r][c] = 0.f;

    const float2* __restrict__ wsrc2 = (const float2*)wT;  // 2304 float2 per chunk

    // stage chunk 0 (ci 0,1) into buf 0
    {
        float2* smw2 = (float2*)(sm + 208);
#pragma unroll
        for (int j = 0; j < 9; j++)
            smw2[tid + j * 256] = wsrc2[tid + j * 256];
        if (tid < 200)
            sm[tid] = p_ok ? in[p_ci * HW + p_goff] : 0.f;
    }
    __syncthreads();

    for (int ch = 0; ch < 128; ++ch) {
        const int cur = ch & 1;
        const float* buf = sm + cur * 4816;
        float2 wreg[9];
        float pv = 0.f;
        if (ch < 127) {  // issue prefetch of chunk ch+1 (hides L2 latency under FMAs)
            const float2* __restrict__ wsrcn = wsrc2 + (size_t)(ch + 1) * 2304;
#pragma unroll
            for (int j = 0; j < 9; j++) wreg[j] = wsrcn[tid + j * 256];
            if (tid < 200)
                pv = p_ok ? in[((ch + 1) * 2 + p_ci) * HW + p_goff] : 0.f;
        }
        // compute chunk ch from buf
#pragma unroll
        for (int ci = 0; ci < 2; ci++) {
#pragma unroll
            for (int ky = 0; ky < 3; ky++) {
                float in10[10];
                int prow = (ci * 10 + pg + ky) * 10;
#pragma unroll
                for (int q = 0; q < 10; q++) in10[q] = buf[prow + q];
#pragma unroll
                for (int kx = 0; kx < 3; kx++) {
                    float w8[8];
                    int wb = 208 + ((ci * 3 + ky) * 3 + kx) * 256 + co0;
#pragma unroll
                    for (int r = 0; r < 8; r++) w8[r] = buf[wb + r];
#pragma unroll
                    for (int r = 0; r < 8; r++)
#pragma unroll
                        for (int c = 0; c < 8; c++)
                            acc[r][c] = fmaf(w8[r], in10[c + kx], acc[r][c]);
                }
            }
        }
        if (ch < 127) {  // write prefetched chunk to the other buffer
            float* nbuf = sm + (cur ^ 1) * 4816;
            float2* nw2 = (float2*)(nbuf + 208);
#pragma unroll
            for (int j = 0; j < 9; j++) nw2[tid + j * 256] = wreg[j];
            if (tid < 200) nbuf[tid] = pv;
            __syncthreads();  // one barrier per chunk
        }
    }
    // bias + relu in registers: acc becomes t
    {
        float bias[8];
#pragma unroll
        for (int r = 0; r < 8; r++) bias[r] = convb[co0 + r];
#pragma unroll
        for (int r = 0; r < 8; r++)
#pragma unroll
            for (int c = 0; c < 8; c++) {
                float tv = acc[r][c] + bias[r];
                acc[r][c] = tv > 0.f ? tv : 0.f;
            }
    }
    // heads: 15 heads in chunks of 3; per-thread partial over its 8 co,
    // then deterministic 32-way tree over cg in LDS. part layout: [cg][px*3+h'] pad 196.
    for (int hc = 0; hc < 15; hc += 3) {
        float hw3[3][8];
#pragma unroll
        for (int h3 = 0; h3 < 3; h3++)
#pragma unroll
            for (int r = 0; r < 8; r++)
                hw3[h3][r] = headw[(hc + h3) * 256 + co0 + r];
        float part[3][8];
#pragma unroll
        for (int h3 = 0; h3 < 3; h3++)
#pragma unroll
            for (int c = 0; c < 8; c++) part[h3][c] = 0.f;
#pragma unroll
        for (int r = 0; r < 8; r++)
#pragma unroll
            for (int c = 0; c < 8; c++) {
                float tv = acc[r][c];
#pragma unroll
                for (int h3 = 0; h3 < 3; h3++)
                    part[h3][c] = fmaf(hw3[h3][r], tv, part[h3][c]);
            }
        __syncthreads();  // previous chunk's reads (or conv phase) done
        int base = cg * 196 + pg * 24;
#pragma unroll
        for (int c = 0; c < 8; c++)
#pragma unroll
            for (int h3 = 0; h3 < 3; h3++)
                sm[base + c * 3 + h3] = part[h3][c];
        __syncthreads();
        if (tid < 192) {
            int px = tid / 3, h3 = tid % 3;
            int h = hc + h3;
            float sum = 0.f;
#pragma unroll
            for (int g = 0; g < 32; g++) sum += sm[g * 196 + tid];
            sum += headb[h];
            int row = px >> 3, col = px & 7;
            int gy = y0 + row, gx = x0 + col;
            if (gy < H && gx < W) {
                int pix = gy * W + gx;
                if (h < 3) {
                    scores[soff + pix * 3 + h] = sum;
                } else {
                    int ch2 = h - 3;
                    deltas[((size_t)(soff + pix * 3 + (ch2 >> 2))) * 4 + (ch2 & 3)] = sum;
                }
            }
        }
    }
}

// ---------------- kernel 3: per-level exact top-k (radix select) ----------------
// Writes sort keys directly: key = (~flip(score) << 32) | (level<<24 | idx)
// Per-wave histograms (16x256) cut hot-bin LDS-atomic serialization ~16x.
__global__ __launch_bounds__(1024) void k_topk(
    const float* __restrict__ scores, u64* __restrict__ key) {
    const int l = blockIdx.x;
    const int Nl = c_Nl[l], off = c_soff[l], k = c_k[l];
    const int base = l * 1000;
    const int tid = threadIdx.x;
    const u32 lshift = (u32)l << 24;
    __shared__ u32 histw[16][256];
    __shared__ u32 hist[256];
    __shared__ u32 sh_prefix, sh_m, sh_sel, sh_tie;
    __shared__ u32 tiebuf[2048];
    if (tid == 0) { sh_sel = 0; sh_tie = 0; }
    __syncthreads();

    if (k == Nl) {  // take everything (level 4)
        for (int i = tid; i < Nl; i += 1024) {
            u32 p = atomicAdd(&sh_sel, 1u);
            u32 k32 = flipf(scores[off + i]);
            key[base + p] = ((u64)(~k32) << 32) | (u64)(lshift | (u32)i);
        }
        return;
    }
    const int wid = tid >> 6;
    u32 prefix = 0, m = (u32)k;
    for (int p = 0; p < 4; p++) {
        int shift = 24 - 8 * p;
        for (int b = tid; b < 4096; b += 1024) ((u32*)histw)[b] = 0;
        __syncthreads();
        for (int i = tid; i < Nl; i += 1024) {
            u32 k32 = flipf(scores[off + i]);
            if (p == 0 || (k32 >> (shift + 8)) == prefix)
                atomicAdd(&histw[wid][(k32 >> shift) & 255u], 1u);
        }
        __syncthreads();
        for (int b = tid; b < 256; b += 1024) {
            u32 s = 0;
#pragma unroll
            for (int w = 0; w < 16; w++) s += histw[w][b];
            hist[b] = s;
        }
        __syncthreads();
        if (tid == 0) {
            u32 cum = 0;
            for (int b = 255; b >= 0; --b) {
                u32 c = hist[b];
                if (cum + c >= m) { sh_prefix = (prefix << 8) | (u32)b; sh_m = m - cum; break; }
                cum += c;
            }
        }
        __syncthreads();
        prefix = sh_prefix; m = sh_m;
        __syncthreads();
    }
    // compact: strictly greater -> selected; equal -> tie list
    for (int i = tid; i < Nl; i += 1024) {
        u32 k32 = flipf(scores[off + i]);
        if (k32 > prefix) {
            u32 p = atomicAdd(&sh_sel, 1u);
            key[base + p] = ((u64)(~k32) << 32) | (u64)(lshift | (u32)i);
        } else if (k32 == prefix) {
            u32 t = atomicAdd(&sh_tie, 1u);
            if (t < 2048u) tiebuf[t] = (u32)i;
        }
    }
    __syncthreads();
    u32 nsel = sh_sel;
    u32 ntie = sh_tie; if (ntie > 2048u) ntie = 2048u;
    if (ntie != m) {  // need m smallest indices among ties
        for (u32 j = tid; j < 2048; j += 1024) if (j >= ntie) tiebuf[j] = 0xFFFFFFFFu;
        __syncthreads();
        for (u32 ksz = 2; ksz <= 2048; ksz <<= 1) {
            for (u32 jj = ksz >> 1; jj > 0; jj >>= 1) {
                for (u32 i2 = tid; i2 < 2048; i2 += 1024) {
                    u32 ixj = i2 ^ jj;
                    if (ixj > i2) {
                        u32 a = tiebuf[i2], b = tiebuf[ixj];
                        bool up = ((i2 & ksz) == 0);
                        if ((a > b) == up) { tiebuf[i2] = b; tiebuf[ixj] = a; }
                    }
                }
                __syncthreads();
            }
        }
    }
    for (u32 j = tid; j < m; j += 1024)
        key[base + nsel + j] = ((u64)(~prefix) << 32) | (u64)(lshift | tiebuf[j]);
}

// ---------------- kernel 4: global bitonic sort + inline decode ----------------
__global__ __launch_bounds__(1024) void k_sort(
    const u64* __restrict__ key, const float* __restrict__ deltas, DecParams P,
    float* __restrict__ sboxes, float* __restrict__ sob, u32* __restrict__ svalid) {
    __shared__ u64 sk[8192];
    const int tid = threadIdx.x;
    for (int i = tid; i < 8192; i += 1024) sk[i] = (i < NCAND) ? key[i] : ~0ull;
    __syncthreads();
    for (u32 ksz = 2; ksz <= 8192; ksz <<= 1) {
        for (u32 j = ksz >> 1; j > 0; j >>= 1) {
            for (u32 i = tid; i < 8192; i += 1024) {
                u32 ixj = i ^ j;
                if (ixj > i) {
                    u64 a = sk[i], b = sk[ixj];
                    bool up = ((i & ksz) == 0);
                    if ((a > b) == up) { sk[i] = b; sk[ixj] = a; }
                }
            }
            __syncthreads();
        }
    }
    const float CLAMP = 4.135166556742356f;  // log(1000/16)
    for (int s = tid; s < NCAND; s += 1024) {
        u32 info = (u32)sk[s];
        int l = info >> 24, idx = info & 0xFFFFFF;
        int W = c_W[l], st = c_stride[l];
        int a = idx % 3, pix = idx / 3;
        int x = pix % W, y = pix / W;
        float ax1 = x * st + P.b[l][a][0];
        float ay1 = y * st + P.b[l][a][1];
        float ax2 = x * st + P.b[l][a][2];
        float ay2 = y * st + P.b[l][a][3];
        float w_ = ax2 - ax1, h_ = ay2 - ay1;
        float cx = ax1 + 0.5f * w_, cy = ay1 + 0.5f * h_;
        const float* d = deltas + ((size_t)(c_soff[l] + idx)) * 4;
        float dx = d[0], dy = d[1];
        float dw = fminf(d[2], CLAMP), dh = fminf(d[3], CLAMP);
        float pcx = dx * w_ + cx, pcy = dy * h_ + cy;
        float pw = expf(dw) * w_, ph = expf(dh) * h_;
        float x1 = pcx - 0.5f * pw, y1 = pcy - 0.5f * ph;
        float x2 = pcx + 0.5f * pw, y2 = pcy + 0.5f * ph;
        x1 = fminf(fmaxf(x1, 0.f), 800.f); y1 = fminf(fmaxf(y1, 0.f), 800.f);
        x2 = fminf(fmaxf(x2, 0.f), 800.f); y2 = fminf(fmaxf(y2, 0.f), 800.f);
        u32 vv = (x2 - x1 >= 0.001f && y2 - y1 >= 0.001f) ? 1u : 0u;
        float offv = (float)l * 801.0f;
        sboxes[s * 4 + 0] = x1; sboxes[s * 4 + 1] = y1;
        sboxes[s * 4 + 2] = x2; sboxes[s * 4 + 3] = y2;
        sob[s * 4 + 0] = x1 + offv; sob[s * 4 + 1] = y1 + offv;
        sob[s * 4 + 2] = x2 + offv; sob[s * 4 + 3] = y2 + offv;
        svalid[s] = vv;
    }
}

// ---------------- kernel 5: IoU suppression bitmask ----------------
__global__ __launch_bounds__(256) void k_mask(
    const float* __restrict__ sob, u64* __restrict__ mask) {
    int gid = blockIdx.x * 256 + threadIdx.x;
    const int total = NCAND * WORDS;
    if (gid >= total) return;
    int i = gid / WORDS, w = gid - i * WORDS;
    float bx1 = sob[i * 4], by1 = sob[i * 4 + 1], bx2 = sob[i * 4 + 2], by2 = sob[i * 4 + 3];
    float ai = (bx2 - bx1) * (by2 - by1);
    u64 bits = 0;
    int j0 = w * 64;
    for (int b = 0; b < 64; b++) {
        int j = j0 + b;
        if (j < NCAND && j > i) {
            float cx1 = sob[j * 4], cy1 = sob[j * 4 + 1], cx2 = sob[j * 4 + 2], cy2 = sob[j * 4 + 3];
            float lt0 = fmaxf(bx1, cx1), lt1 = fmaxf(by1, cy1);
            float rb0 = fminf(bx2, cx2), rb1 = fminf(by2, cy2);
            float ww = fmaxf(rb0 - lt0, 0.f), hh = fmaxf(rb1 - lt1, 0.f);
            float inter = ww * hh;
            float aj = (cx2 - cx1) * (cy2 - cy1);
            float u = ai + aj - inter;
            float iou = inter / u;           // 0/0 -> NaN -> no suppression (matches ref)
            if (iou > 0.7f) bits |= (1ull << b);
        }
    }
    mask[(size_t)i * WORDS + w] = bits;
}

// ---------------- kernel 6: tiled greedy NMS scan (single block, 1024 thr) ----------------
__global__ __launch_bounds__(1024) void k_scan(
    const u64* __restrict__ mask, const u32* __restrict__ svalid,
    u64* __restrict__ keepg) {
    __shared__ u64 keep[WORDS];
    __shared__ u32 ormL[WORDS], ormH[WORDS];
    const int tid = threadIdx.x;
    if (tid < WORDS) {
        u64 w0 = 0;
        for (int b = 0; b < 64; b++) {
            int idx = tid * 64 + b;
            if (idx < NCAND && svalid[idx]) w0 |= (1ull << b);
        }
        keep[tid] = w0; ormL[tid] = 0; ormH[tid] = 0;
    }
    __syncthreads();
    for (int t = 0; t < WORDS; t++) {
        if (tid < 64) {  // wave 0: serial intra-tile resolve on the diagonal word
            int row = t * 64 + tid;
            u64 d = (row < NCAND) ? mask[(size_t)row * WORDS + t] : 0ull;
            u32 dlo = (u32)d, dhi = (u32)(d >> 32);
            u64 cur = keep[t];
            u64 pending = cur;
            while (pending) {
                int b = __builtin_ctzll(pending);
                pending &= pending - 1;
                u64 mb = ((u64)__shfl(dhi, b, 64) << 32) | (u64)__shfl(dlo, b, 64);
                cur &= ~mb;       // row b is alive (pending only holds survivors)
                pending &= ~mb;   // skip rows it just suppressed
            }
            if (tid == 0) keep[t] = cur;
        }
        __syncthreads();
        u64 kw = keep[t];
        int nW = WORDS - 1 - t;
        for (int task = tid; task < 64 * nW; task += 1024) {
            int r = task / nW, w = t + 1 + (task - r * nW);
            if ((kw >> r) & 1ull) {
                u64 mrow = mask[(size_t)(t * 64 + r) * WORDS + w];
                if (mrow) {
                    atomicOr(&ormL[w], (u32)mrow);
                    atomicOr(&ormH[w], (u32)(mrow >> 32));
                }
            }
        }
        __syncthreads();
        if (tid > t && tid < WORDS) {
            keep[tid] &= ~(((u64)ormH[tid] << 32) | (u64)ormL[tid]);
            ormL[tid] = 0; ormH[tid] = 0;
        }
        __syncthreads();
    }
    if (tid < WORDS) keepg[tid] = keep[tid];
}

// ---------------- kernel 7: final gather (kept first, then suppressed in index order) ----------------
__global__ __launch_bounds__(1024) void k_out(
    const u64* __restrict__ keepg, const float* __restrict__ sboxes,
    float* __restrict__ out) {
    __shared__ u32 sc[1024];
    __shared__ u64 kw[WORDS];
    const int tid = threadIdx.x;
    if (tid < WORDS) kw[tid] = keepg[tid];
    __syncthreads();
    const int i0 = tid * 5;
    u32 cnt = 0;
    for (int e = 0; e < 5; e++) {
        int i = i0 + e;
        if (i < NCAND) cnt += (u32)((kw[i >> 6] >> (i & 63)) & 1ull);
    }
    sc[tid] = cnt;
    __syncthreads();
    for (int off = 1; off < 1024; off <<= 1) {
        u32 v = (tid >= off) ? sc[tid - off] : 0;
        __syncthreads();
        sc[tid] += v;
        __syncthreads();
    }
    u32 incl = sc[tid];
    u32 total = sc[1023];
    u32 kr = incl - cnt;  // kept before my first element
    for (int e = 0; e < 5; e++) {
        int i = i0 + e;
        if (i < NCAND) {
            bool kp = (kw[i >> 6] >> (i & 63)) & 1ull;
            if (kp) {
                if (kr < 1000u) {
                    out[kr * 4 + 0] = sboxes[i * 4 + 0];
                    out[kr * 4 + 1] = sboxes[i * 4 + 1];
                    out[kr * 4 + 2] = sboxes[i * 4 + 2];
                    out[kr * 4 + 3] = sboxes[i * 4 + 3];
                }
                kr++;
            } else {
                u32 slot = total + (u32)i - kr;
                if (slot < 1000u) {
                    out[slot * 4 + 0] = sboxes[i * 4 + 0];
                    out[slot * 4 + 1] = sboxes[i * 4 + 1];
                    out[slot * 4 + 2] = sboxes[i * 4 + 2];
                    out[slot * 4 + 3] = sboxes[i * 4 + 3];
                }
            }
        }
    }
}

// ---------------- host ----------------
extern "C" void kernel_launch(void* const* d_in, const int* in_sizes, int n_in,
                              void* d_out, int out_size, void* d_ws, size_t ws_size,
                              hipStream_t stream) {
    (void)in_sizes; (void)n_in; (void)out_size; (void)ws_size;
    FeatPtrs fp;
    for (int i = 0; i < 5; i++) fp.p[i] = (const float*)d_in[i];
    const float* conv_w = (const float*)d_in[5];
    const float* conv_b = (const float*)d_in[6];
    const float* cls_w  = (const float*)d_in[7];
    const float* cls_b  = (const float*)d_in[8];
    const float* bbox_w = (const float*)d_in[9];
    const float* bbox_b = (const float*)d_in[10];

    char* ws = (char*)d_ws;
    float* wT     = (float*)(ws + OFF_WT);
    float* headw  = (float*)(ws + OFF_HEADW);
    float* headb  = (float*)(ws + OFF_HEADB);
    float* scores = (float*)(ws + OFF_SCORES);
    float* deltas = (float*)(ws + OFF_DELTAS);
    u64*   key    = (u64*)(ws + OFF_KEY);
    float* sboxes = (float*)(ws + OFF_SBOX);
    float* sob    = (float*)(ws + OFF_SOB);
    u32*   svalid = (u32*)(ws + OFF_SVAL);
    u64*   maskp  = (u64*)(ws + OFF_MASK);
    u64*   keepg  = (u64*)(ws + OFF_KEEP);

    k_prep<<<2304, 256, 0, stream>>>(conv_w, cls_w, cls_b, bbox_w, bbox_b, wT, headw, headb);

    // one launch for all 5 levels: 625+169+49+16+4 = 863 tiles
    k_conv<<<863, 256, 0, stream>>>(fp, wT, conv_b, headw, headb, scores, deltas);

    k_topk<<<5, 1024, 0, stream>>>(scores, key);

    DecParams dp;
    {
        const double sz[5] = {32.0, 64.0, 128.0, 256.0, 512.0};
        const double rt[3] = {0.5, 1.0, 2.0};
        for (int l = 0; l < 5; l++)
            for (int a = 0; a < 3; a++) {
                double hr = sqrt(rt[a]);
                double wr = 1.0 / hr;
                double w = wr * sz[l], h = hr * sz[l];
                dp.b[l][a][0] = (float)nearbyint(-w / 2.0);
                dp.b[l][a][1] = (float)nearbyint(-h / 2.0);
                dp.b[l][a][2] = (float)nearbyint(w / 2.0);
                dp.b[l][a][3] = (float)nearbyint(h / 2.0);
            }
    }
    k_sort<<<1, 1024, 0, stream>>>(key, deltas, dp, sboxes, sob, svalid);
    k_mask<<<(NCAND * WORDS + 255) / 256, 256, 0, stream>>>(sob, maskp);
    k_scan<<<1, 1024, 0, stream>>>(maskp, svalid, keepg);
    k_out<<<1, 1024, 0, stream>>>(keepg, sboxes, (float*)d_out);
}

// Round 6
// 1874.414 us; speedup vs baseline: 1.0668x; 1.0668x over previous
//
#include <hip/hip_runtime.h>
#include <cmath>

typedef unsigned int u32;
typedef unsigned long long u64;

// address-space-qualified typedefs for global_load_lds
typedef __attribute__((address_space(1))) const unsigned int gu32;
typedef __attribute__((address_space(3))) unsigned int lu32;

#define NCAND 4507
#define WORDS 71              // ceil(4507/64)
#define ROWS_AL (WORDS * 64)  // 4544
#define TOTS 159882           // total scores across levels

__constant__ int c_W[5]      = {200, 100, 50, 25, 13};
__constant__ int c_stride[5] = {4, 8, 16, 32, 61};
__constant__ int c_Nl[5]     = {120000, 30000, 7500, 1875, 507};
__constant__ int c_soff[5]   = {0, 120000, 150000, 157500, 159375};
__constant__ int c_k[5]      = {1000, 1000, 1000, 1000, 507};

// unified conv grid: tiles per level (8x8 px tiles): 625,169,49,16,4
__constant__ int cv_boff[6]  = {0, 625, 794, 843, 859, 863};

struct DecParams { float b[5][3][4]; };
struct FeatPtrs { const float* p[5]; };

__device__ __forceinline__ u32 flipf(float f) {
    u32 u = __float_as_uint(f);
    return (u & 0x80000000u) ? ~u : (u | 0x80000000u);
}

// ---------------- workspace layout ----------------
constexpr size_t AL(size_t x) { return (x + 255) & ~(size_t)255; }
constexpr size_t OFF_WT     = 0;                                   // 589824 f
constexpr size_t OFF_HEADW  = AL(OFF_WT + 589824 * 4);             // 15*256 f
constexpr size_t OFF_HEADB  = AL(OFF_HEADW + 3840 * 4);            // 15 f
constexpr size_t OFF_SCORES = AL(OFF_HEADB + 64);                  // TOTS f
constexpr size_t OFF_DELTAS = AL(OFF_SCORES + (size_t)TOTS * 4);   // TOTS*4 f
constexpr size_t OFF_KEY    = AL(OFF_DELTAS + (size_t)TOTS * 16);  // NCAND u64
constexpr size_t OFF_SBOX   = AL(OFF_KEY + (size_t)NCAND * 8);     // NCAND*4 f
constexpr size_t OFF_SOB    = AL(OFF_SBOX + (size_t)NCAND * 16);   // NCAND*4 f
constexpr size_t OFF_SVAL   = AL(OFF_SOB + (size_t)NCAND * 16);    // NCAND u32
constexpr size_t OFF_MASK   = AL(OFF_SVAL + (size_t)NCAND * 4);    // ROWS_AL*WORDS u64
constexpr size_t OFF_KEEP   = AL(OFF_MASK + (size_t)ROWS_AL * WORDS * 8); // WORDS u64

// ---------------- kernel 1: weight prep ----------------
// wT[ci][ky][kx][co]  from conv_w[co][ci][ky][kx]; combined head weights/bias.
__global__ __launch_bounds__(256) void k_prep(
    const float* __restrict__ cw, const float* __restrict__ clsw,
    const float* __restrict__ clsb, const float* __restrict__ bw,
    const float* __restrict__ bb, float* __restrict__ wT,
    float* __restrict__ headw, float* __restrict__ headb) {
    int i = blockIdx.x * 256 + threadIdx.x;
    if (i < 589824) {
        int co = i & 255, r = i >> 8;
        int kx = r % 3, ky = (r / 3) % 3, ci = r / 9;
        wT[i] = cw[(((co << 8) + ci) * 3 + ky) * 3 + kx];
    }
    if (i < 3840) {
        int h = i >> 8, ci = i & 255;
        headw[i] = (h < 3) ? clsw[h * 256 + ci] : bw[(h - 3) * 256 + ci];
    }
    if (i < 15) headb[i] = (i < 3) ? clsb[i] : bb[i - 3];
}

// ---------------- kernel 2: fused conv3x3+ReLU + 1x1 heads, ALL LEVELS ----------------
// Block: 256 threads -> 8x8 pixel tile, all 256 output channels.
// Thread (cg,pg): 8 co x 8 px register micro-tile.
// Double-buffered 2-ci chunks; next chunk's WEIGHTS staged via
// __builtin_amdgcn_global_load_lds (zero VGPR cost, 18 x 1KB blocks split
// over 4 waves, issued before the FMA block; __syncthreads drains vmcnt).
// Patch (200 lanes) = 1-register early load + late ds_write.
// LDS = 2 x (200 patch + 8 pad + 4608 w) = 9632 f = 38.5 KB -> 4 blocks/CU.
// Accumulation order ci-ascending: bit-identical to r4/r5 (absmax 0.0).
// VGPR history: r4 (no prefetch) 128 = 16 waves/CU; r5 (reg prefetch) 164 ->
// occupancy halved. This version must stay <=128 (go/no-go check in profile).
__global__ __launch_bounds__(256) void k_conv(
    FeatPtrs fp, const float* __restrict__ wT,
    const float* __restrict__ convb, const float* __restrict__ headw,
    const float* __restrict__ headb, float* __restrict__ scores,
    float* __restrict__ deltas) {
    __shared__ float sm[9632];  // 2 bufs @ 0/4816: [patch 200][pad 8][w 4608]; head: part[32][196]
    const int tid = threadIdx.x;
    const int cg = tid >> 3, pg = tid & 7, co0 = cg << 3;
    const int lane = tid & 63, wv = tid >> 6;

    // level lookup
    const int bid = blockIdx.x;
    int l = 0;
#pragma unroll
    for (int q = 1; q < 5; q++) if (bid >= cv_boff[q]) l = q;
    const int H = c_W[l], W = H;
    const int soff = c_soff[l];
    const float* __restrict__ in = fp.p[l];
    const int t = bid - cv_boff[l];
    const int tilesx = (W + 7) >> 3;
    const int tx = t % tilesx, ty = t / tilesx;
    const int x0 = tx * 8, y0 = ty * 8;
    const int HW = H * W;

    // this thread's fixed patch-staging slot (tid<200): [ci 2][py 10][px 10]
    const int p_ci = tid / 100, p_rr = tid - p_ci * 100;
    const int p_py = p_rr / 10, p_px = p_rr - p_py * 10;
    const int p_gy = y0 - 1 + p_py, p_gx = x0 - 1 + p_px;
    const bool p_ok = (tid < 200) && (p_gy >= 0) && (p_gy < H) && (p_gx >= 0) && (p_gx < W);
    const int p_goff = p_ok ? (p_gy * W + p_gx) : 0;

    float acc[8][8];
#pragma unroll
    for (int r = 0; r < 8; r++)
#pragma unroll
        for (int c = 0; c < 8; c++) acc[r][c] = 0.f;

    // prologue: stage chunk 0 (ci 0,1) into buf 0 (weights async, patch direct)
    {
        for (int j = wv; j < 18; j += 4) {
            const float* g = wT + j * 256 + lane * 4;
            float* ldst = sm + 208 + j * 256;
            __builtin_amdgcn_global_load_lds((gu32*)g, (lu32*)ldst, 16, 0, 0);
        }
        if (tid < 200)
            sm[tid] = p_ok ? in[p_ci * HW + p_goff] : 0.f;
    }
    __syncthreads();

    for (int ch = 0; ch < 128; ++ch) {
        const int cur = ch & 1;
        const float* buf = sm + cur * 4816;
        float pv = 0.f;
        if (ch < 127) {  // issue next chunk's staging before compute
            float* nbuf = sm + (cur ^ 1) * 4816;
            const float* wn = wT + (size_t)(ch + 1) * 4608;
            for (int j = wv; j < 18; j += 4) {
                const float* g = wn + j * 256 + lane * 4;
                float* ldst = nbuf + 208 + j * 256;
                __builtin_amdgcn_global_load_lds((gu32*)g, (lu32*)ldst, 16, 0, 0);
            }
            if (tid < 200)
                pv = p_ok ? in[((ch + 1) * 2 + p_ci) * HW + p_goff] : 0.f;
        }
        // compute chunk ch from buf (2 input channels)
#pragma unroll
        for (int ci = 0; ci < 2; ci++) {
#pragma unroll
            for (int ky = 0; ky < 3; ky++) {
                float in10[10];
                int prow = (ci * 10 + pg + ky) * 10;
#pragma unroll
                for (int q = 0; q < 10; q++) in10[q] = buf[prow + q];
#pragma unroll
                for (int kx = 0; kx < 3; kx++) {
                    float w8[8];
                    int wb = 208 + ((ci * 3 + ky) * 3 + kx) * 256 + co0;
#pragma unroll
                    for (int r = 0; r < 8; r++) w8[r] = buf[wb + r];
#pragma unroll
                    for (int r = 0; r < 8; r++)
#pragma unroll
                        for (int c = 0; c < 8; c++)
                            acc[r][c] = fmaf(w8[r], in10[c + kx], acc[r][c]);
                }
            }
        }
        if (ch < 127) {  // late patch write, then barrier (drains async loads too)
            float* nbuf = sm + (cur ^ 1) * 4816;
            if (tid < 200) nbuf[tid] = pv;
            __syncthreads();
        }
    }
    // bias + relu in registers: acc becomes t
    {
        float bias[8];
#pragma unroll
        for (int r = 0; r < 8; r++) bias[r] = convb[co0 + r];
#pragma unroll
        for (int r = 0; r < 8; r++)
#pragma unroll
            for (int c = 0; c < 8; c++) {
                float tv = acc[r][c] + bias[r];
                acc[r][c] = tv > 0.f ? tv : 0.f;
            }
    }
    // heads: 15 heads in chunks of 3; per-thread partial over its 8 co,
    // then deterministic 32-way tree over cg in LDS. part layout: [cg][px*3+h'] pad 196.
    for (int hc = 0; hc < 15; hc += 3) {
        float hw3[3][8];
#pragma unroll
        for (int h3 = 0; h3 < 3; h3++)
#pragma unroll
            for (int r = 0; r < 8; r++)
                hw3[h3][r] = headw[(hc + h3) * 256 + co0 + r];
        float part[3][8];
#pragma unroll
        for (int h3 = 0; h3 < 3; h3++)
#pragma unroll
            for (int c = 0; c < 8; c++) part[h3][c] = 0.f;
#pragma unroll
        for (int r = 0; r < 8; r++)
#pragma unroll
            for (int c = 0; c < 8; c++) {
                float tv = acc[r][c];
#pragma unroll
                for (int h3 = 0; h3 < 3; h3++)
                    part[h3][c] = fmaf(hw3[h3][r], tv, part[h3][c]);
            }
        __syncthreads();  // previous phase's reads done
        int base = cg * 196 + pg * 24;
#pragma unroll
        for (int c = 0; c < 8; c++)
#pragma unroll
            for (int h3 = 0; h3 < 3; h3++)
                sm[base + c * 3 + h3] = part[h3][c];
        __syncthreads();
        if (tid < 192) {
            int px = tid / 3, h3 = tid % 3;
            int h = hc + h3;
            float sum = 0.f;
#pragma unroll
            for (int g = 0; g < 32; g++) sum += sm[g * 196 + tid];
            sum += headb[h];
            int row = px >> 3, col = px & 7;
            int gy = y0 + row, gx = x0 + col;
            if (gy < H && gx < W) {
                int pix = gy * W + gx;
                if (h < 3) {
                    scores[soff + pix * 3 + h] = sum;
                } else {
                    int ch2 = h - 3;
                    deltas[((size_t)(soff + pix * 3 + (ch2 >> 2))) * 4 + (ch2 & 3)] = sum;
                }
            }
        }
    }
}

// ---------------- kernel 3: per-level exact top-k (radix select) ----------------
// Writes sort keys directly: key = (~flip(score) << 32) | (level<<24 | idx)
// Per-wave histograms (16x256) cut hot-bin LDS-atomic serialization ~16x.
__global__ __launch_bounds__(1024) void k_topk(
    const float* __restrict__ scores, u64* __restrict__ key) {
    const int l = blockIdx.x;
    const int Nl = c_Nl[l], off = c_soff[l], k = c_k[l];
    const int base = l * 1000;
    const int tid = threadIdx.x;
    const u32 lshift = (u32)l << 24;
    __shared__ u32 histw[16][256];
    __shared__ u32 hist[256];
    __shared__ u32 sh_prefix, sh_m, sh_sel, sh_tie;
    __shared__ u32 tiebuf[2048];
    if (tid == 0) { sh_sel = 0; sh_tie = 0; }
    __syncthreads();

    if (k == Nl) {  // take everything (level 4)
        for (int i = tid; i < Nl; i += 1024) {
            u32 p = atomicAdd(&sh_sel, 1u);
            u32 k32 = flipf(scores[off + i]);
            key[base + p] = ((u64)(~k32) << 32) | (u64)(lshift | (u32)i);
        }
        return;
    }
    const int wid = tid >> 6;
    u32 prefix = 0, m = (u32)k;
    for (int p = 0; p < 4; p++) {
        int shift = 24 - 8 * p;
        for (int b = tid; b < 4096; b += 1024) ((u32*)histw)[b] = 0;
        __syncthreads();
        for (int i = tid; i < Nl; i += 1024) {
            u32 k32 = flipf(scores[off + i]);
            if (p == 0 || (k32 >> (shift + 8)) == prefix)
                atomicAdd(&histw[wid][(k32 >> shift) & 255u], 1u);
        }
        __syncthreads();
        for (int b = tid; b < 256; b += 1024) {
            u32 s = 0;
#pragma unroll
            for (int w = 0; w < 16; w++) s += histw[w][b];
            hist[b] = s;
        }
        __syncthreads();
        if (tid == 0) {
            u32 cum = 0;
            for (int b = 255; b >= 0; --b) {
                u32 c = hist[b];
                if (cum + c >= m) { sh_prefix = (prefix << 8) | (u32)b; sh_m = m - cum; break; }
                cum += c;
            }
        }
        __syncthreads();
        prefix = sh_prefix; m = sh_m;
        __syncthreads();
    }
    // compact: strictly greater -> selected; equal -> tie list
    for (int i = tid; i < Nl; i += 1024) {
        u32 k32 = flipf(scores[off + i]);
        if (k32 > prefix) {
            u32 p = atomicAdd(&sh_sel, 1u);
            key[base + p] = ((u64)(~k32) << 32) | (u64)(lshift | (u32)i);
        } else if (k32 == prefix) {
            u32 t = atomicAdd(&sh_tie, 1u);
            if (t < 2048u) tiebuf[t] = (u32)i;
        }
    }
    __syncthreads();
    u32 nsel = sh_sel;
    u32 ntie = sh_tie; if (ntie > 2048u) ntie = 2048u;
    if (ntie != m) {  // need m smallest indices among ties
        for (u32 j = tid; j < 2048; j += 1024) if (j >= ntie) tiebuf[j] = 0xFFFFFFFFu;
        __syncthreads();
        for (u32 ksz = 2; ksz <= 2048; ksz <<= 1) {
            for (u32 jj = ksz >> 1; jj > 0; jj >>= 1) {
                for (u32 i2 = tid; i2 < 2048; i2 += 1024) {
                    u32 ixj = i2 ^ jj;
                    if (ixj > i2) {
                        u32 a = tiebuf[i2], b = tiebuf[ixj];
                        bool up = ((i2 & ksz) == 0);
                        if ((a > b) == up) { tiebuf[i2] = b; tiebuf[ixj] = a; }
                    }
                }
                __syncthreads();
            }
        }
    }
    for (u32 j = tid; j < m; j += 1024)
        key[base + nsel + j] = ((u64)(~prefix) << 32) | (u64)(lshift | tiebuf[j]);
}

// ---------------- kernel 4: global bitonic sort + inline decode ----------------
__global__ __launch_bounds__(1024) void k_sort(
    const u64* __restrict__ key, const float* __restrict__ deltas, DecParams P,
    float* __restrict__ sboxes, float* __restrict__ sob, u32* __restrict__ svalid) {
    __shared__ u64 sk[8192];
    const int tid = threadIdx.x;
    for (int i = tid; i < 8192; i += 1024) sk[i] = (i < NCAND) ? key[i] : ~0ull;
    __syncthreads();
    for (u32 ksz = 2; ksz <= 8192; ksz <<= 1) {
        for (u32 j = ksz >> 1; j > 0; j >>= 1) {
            for (u32 i = tid; i < 8192; i += 1024) {
                u32 ixj = i ^ j;
                if (ixj > i) {
                    u64 a = sk[i], b = sk[ixj];
                    bool up = ((i & ksz) == 0);
                    if ((a > b) == up) { sk[i] = b; sk[ixj] = a; }
                }
            }
            __syncthreads();
        }
    }
    const float CLAMP = 4.135166556742356f;  // log(1000/16)
    for (int s = tid; s < NCAND; s += 1024) {
        u32 info = (u32)sk[s];
        int l = info >> 24, idx = info & 0xFFFFFF;
        int W = c_W[l], st = c_stride[l];
        int a = idx % 3, pix = idx / 3;
        int x = pix % W, y = pix / W;
        float ax1 = x * st + P.b[l][a][0];
        float ay1 = y * st + P.b[l][a][1];
        float ax2 = x * st + P.b[l][a][2];
        float ay2 = y * st + P.b[l][a][3];
        float w_ = ax2 - ax1, h_ = ay2 - ay1;
        float cx = ax1 + 0.5f * w_, cy = ay1 + 0.5f * h_;
        const float* d = deltas + ((size_t)(c_soff[l] + idx)) * 4;
        float dx = d[0], dy = d[1];
        float dw = fminf(d[2], CLAMP), dh = fminf(d[3], CLAMP);
        float pcx = dx * w_ + cx, pcy = dy * h_ + cy;
        float pw = expf(dw) * w_, ph = expf(dh) * h_;
        float x1 = pcx - 0.5f * pw, y1 = pcy - 0.5f * ph;
        float x2 = pcx + 0.5f * pw, y2 = pcy + 0.5f * ph;
        x1 = fminf(fmaxf(x1, 0.f), 800.f); y1 = fminf(fmaxf(y1, 0.f), 800.f);
        x2 = fminf(fmaxf(x2, 0.f), 800.f); y2 = fminf(fmaxf(y2, 0.f), 800.f);
        u32 vv = (x2 - x1 >= 0.001f && y2 - y1 >= 0.001f) ? 1u : 0u;
        float offv = (float)l * 801.0f;
        sboxes[s * 4 + 0] = x1; sboxes[s * 4 + 1] = y1;
        sboxes[s * 4 + 2] = x2; sboxes[s * 4 + 3] = y2;
        sob[s * 4 + 0] = x1 + offv; sob[s * 4 + 1] = y1 + offv;
        sob[s * 4 + 2] = x2 + offv; sob[s * 4 + 3] = y2 + offv;
        svalid[s] = vv;
    }
}

// ---------------- kernel 5: IoU suppression bitmask ----------------
__global__ __launch_bounds__(256) void k_mask(
    const float* __restrict__ sob, u64* __restrict__ mask) {
    int gid = blockIdx.x * 256 + threadIdx.x;
    const int total = NCAND * WORDS;
    if (gid >= total) return;
    int i = gid / WORDS, w = gid - i * WORDS;
    float bx1 = sob[i * 4], by1 = sob[i * 4 + 1], bx2 = sob[i * 4 + 2], by2 = sob[i * 4 + 3];
    float ai = (bx2 - bx1) * (by2 - by1);
    u64 bits = 0;
    int j0 = w * 64;
    for (int b = 0; b < 64; b++) {
        int j = j0 + b;
        if (j < NCAND && j > i) {
            float cx1 = sob[j * 4], cy1 = sob[j * 4 + 1], cx2 = sob[j * 4 + 2], cy2 = sob[j * 4 + 3];
            float lt0 = fmaxf(bx1, cx1), lt1 = fmaxf(by1, cy1);
            float rb0 = fminf(bx2, cx2), rb1 = fminf(by2, cy2);
            float ww = fmaxf(rb0 - lt0, 0.f), hh = fmaxf(rb1 - lt1, 0.f);
            float inter = ww * hh;
            float aj = (cx2 - cx1) * (cy2 - cy1);
            float u = ai + aj - inter;
            float iou = inter / u;           // 0/0 -> NaN -> no suppression (matches ref)
            if (iou > 0.7f) bits |= (1ull << b);
        }
    }
    mask[(size_t)i * WORDS + w] = bits;
}

// ---------------- kernel 6: tiled greedy NMS scan (single block, 1024 thr) ----------------
__global__ __launch_bounds__(1024) void k_scan(
    const u64* __restrict__ mask, const u32* __restrict__ svalid,
    u64* __restrict__ keepg) {
    __shared__ u64 keep[WORDS];
    __shared__ u32 ormL[WORDS], ormH[WORDS];
    const int tid = threadIdx.x;
    if (tid < WORDS) {
        u64 w0 = 0;
        for (int b = 0; b < 64; b++) {
            int idx = tid * 64 + b;
            if (idx < NCAND && svalid[idx]) w0 |= (1ull << b);
        }
        keep[tid] = w0; ormL[tid] = 0; ormH[tid] = 0;
    }
    __syncthreads();
    for (int t = 0; t < WORDS; t++) {
        if (tid < 64) {  // wave 0: serial intra-tile resolve on the diagonal word
            int row = t * 64 + tid;
            u64 d = (row < NCAND) ? mask[(size_t)row * WORDS + t] : 0ull;
            u32 dlo = (u32)d, dhi = (u32)(d >> 32);
            u64 cur = keep[t];
            u64 pending = cur;
            while (pending) {
                int b = __builtin_ctzll(pending);
                pending &= pending - 1;
                u64 mb = ((u64)__shfl(dhi, b, 64) << 32) | (u64)__shfl(dlo, b, 64);
                cur &= ~mb;       // row b is alive (pending only holds survivors)
                pending &= ~mb;   // skip rows it just suppressed
            }
            if (tid == 0) keep[t] = cur;
        }
        __syncthreads();
        u64 kw = keep[t];
        int nW = WORDS - 1 - t;
        for (int task = tid; task < 64 * nW; task += 1024) {
            int r = task / nW, w = t + 1 + (task - r * nW);
            if ((kw >> r) & 1ull) {
                u64 mrow = mask[(size_t)(t * 64 + r) * WORDS + w];
                if (mrow) {
                    atomicOr(&ormL[w], (u32)mrow);
                    atomicOr(&ormH[w], (u32)(mrow >> 32));
                }
            }
        }
        __syncthreads();
        if (tid > t && tid < WORDS) {
            keep[tid] &= ~(((u64)ormH[tid] << 32) | (u64)ormL[tid]);
            ormL[tid] = 0; ormH[tid] = 0;
        }
        __syncthreads();
    }
    if (tid < WORDS) keepg[tid] = keep[tid];
}

// ---------------- kernel 7: final gather (kept first, then suppressed in index order) ----------------
__global__ __launch_bounds__(1024) void k_out(
    const u64* __restrict__ keepg, const float* __restrict__ sboxes,
    float* __restrict__ out) {
    __shared__ u32 sc[1024];
    __shared__ u64 kw[WORDS];
    const int tid = threadIdx.x;
    if (tid < WORDS) kw[tid] = keepg[tid];
    __syncthreads();
    const int i0 = tid * 5;
    u32 cnt = 0;
    for (int e = 0; e < 5; e++) {
        int i = i0 + e;
        if (i < NCAND) cnt += (u32)((kw[i >> 6] >> (i & 63)) & 1ull);
    }
    sc[tid] = cnt;
    __syncthreads();
    for (int off = 1; off < 1024; off <<= 1) {
        u32 v = (tid >= off) ? sc[tid - off] : 0;
        __syncthreads();
        sc[tid] += v;
        __syncthreads();
    }
    u32 incl = sc[tid];
    u32 total = sc[1023];
    u32 kr = incl - cnt;  // kept before my first element
    for (int e = 0; e < 5; e++) {
        int i = i0 + e;
        if (i < NCAND) {
            bool kp = (kw[i >> 6] >> (i & 63)) & 1ull;
            if (kp) {
                if (kr < 1000u) {
                    out[kr * 4 + 0] = sboxes[i * 4 + 0];
                    out[kr * 4 + 1] = sboxes[i * 4 + 1];
                    out[kr * 4 + 2] = sboxes[i * 4 + 2];
                    out[kr * 4 + 3] = sboxes[i * 4 + 3];
                }
                kr++;
            } else {
                u32 slot = total + (u32)i - kr;
                if (slot < 1000u) {
                    out[slot * 4 + 0] = sboxes[i * 4 + 0];
                    out[slot * 4 + 1] = sboxes[i * 4 + 1];
                    out[slot * 4 + 2] = sboxes[i * 4 + 2];
                    out[slot * 4 + 3] = sboxes[i * 4 + 3];
                }
            }
        }
    }
}

// ---------------- host ----------------
extern "C" void kernel_launch(void* const* d_in, const int* in_sizes, int n_in,
                              void* d_out, int out_size, void* d_ws, size_t ws_size,
                              hipStream_t stream) {
    (void)in_sizes; (void)n_in; (void)out_size; (void)ws_size;
    FeatPtrs fp;
    for (int i = 0; i < 5; i++) fp.p[i] = (const float*)d_in[i];
    const float* conv_w = (const float*)d_in[5];
    const float* conv_b = (const float*)d_in[6];
    const float* cls_w  = (const float*)d_in[7];
    const float* cls_b  = (const float*)d_in[8];
    const float* bbox_w = (const float*)d_in[9];
    const float* bbox_b = (const float*)d_in[10];

    char* ws = (char*)d_ws;
    float* wT     = (float*)(ws + OFF_WT);
    float* headw  = (float*)(ws + OFF_HEADW);
    float* headb  = (float*)(ws + OFF_HEADB);
    float* scores = (float*)(ws + OFF_SCORES);
    float* deltas = (float*)(ws + OFF_DELTAS);
    u64*   key    = (u64*)(ws + OFF_KEY);
    float* sboxes = (float*)(ws + OFF_SBOX);
    float* sob    = (float*)(ws + OFF_SOB);
    u32*   svalid = (u32*)(ws + OFF_SVAL);
    u64*   maskp  = (u64*)(ws + OFF_MASK);
    u64*   keepg  = (u64*)(ws + OFF_KEEP);

    k_prep<<<2304, 256, 0, stream>>>(conv_w, cls_w, cls_b, bbox_w, bbox_b, wT, headw, headb);

    // one launch for all 5 levels: 625+169+49+16+4 = 863 tiles
    k_conv<<<863, 256, 0, stream>>>(fp, wT, conv_b, headw, headb, scores, deltas);

    k_topk<<<5, 1024, 0, stream>>>(scores, key);

    DecParams dp;
    {
        const double sz[5] = {32.0, 64.0, 128.0, 256.0, 512.0};
        const double rt[3] = {0.5, 1.0, 2.0};
        for (int l = 0; l < 5; l++)
            for (int a = 0; a < 3; a++) {
                double hr = sqrt(rt[a]);
                double wr = 1.0 / hr;
                double w = wr * sz[l], h = hr * sz[l];
                dp.b[l][a][0] = (float)nearbyint(-w / 2.0);
                dp.b[l][a][1] = (float)nearbyint(-h / 2.0);
                dp.b[l][a][2] = (float)nearbyint(w / 2.0);
                dp.b[l][a][3] = (float)nearbyint(h / 2.0);
            }
    }
    k_sort<<<1, 1024, 0, stream>>>(key, deltas, dp, sboxes, sob, svalid);
    k_mask<<<(NCAND * WORDS + 255) / 256, 256, 0, stream>>>(sob, maskp);
    k_scan<<<1, 1024, 0, stream>>>(maskp, svalid, keepg);
    k_out<<<1, 1024, 0, stream>>>(keepg, sboxes, (float*)d_out);
}

// Round 7
// 1551.427 us; speedup vs baseline: 1.2888x; 1.2082x over previous
//
#include <hip/hip_runtime.h>
#include <cmath>

typedef unsigned int u32;
typedef unsigned long long u64;

#define NCAND 4507
#define WORDS 71              // ceil(4507/64)
#define ROWS_AL (WORDS * 64)  // 4544
#define TOTS 159882           // total scores across levels

__constant__ int c_W[5]      = {200, 100, 50, 25, 13};
__constant__ int c_stride[5] = {4, 8, 16, 32, 61};
__constant__ int c_Nl[5]     = {120000, 30000, 7500, 1875, 507};
__constant__ int c_soff[5]   = {0, 120000, 150000, 157500, 159375};
__constant__ int c_k[5]      = {1000, 1000, 1000, 1000, 507};

// unified conv grid: tiles per level (8x8 px tiles): 625,169,49,16,4
__constant__ int cv_boff[6]  = {0, 625, 794, 843, 859, 863};

struct DecParams { float b[5][3][4]; };
struct FeatPtrs { const float* p[5]; };

__device__ __forceinline__ u32 flipf(float f) {
    u32 u = __float_as_uint(f);
    return (u & 0x80000000u) ? ~u : (u | 0x80000000u);
}

// ---------------- workspace layout ----------------
constexpr size_t AL(size_t x) { return (x + 255) & ~(size_t)255; }
constexpr size_t OFF_WT     = 0;                                   // 589824 f
constexpr size_t OFF_HEADW  = AL(OFF_WT + 589824 * 4);             // 15*256 f
constexpr size_t OFF_HEADB  = AL(OFF_HEADW + 3840 * 4);            // 15 f
constexpr size_t OFF_SCORES = AL(OFF_HEADB + 64);                  // TOTS f
constexpr size_t OFF_DELTAS = AL(OFF_SCORES + (size_t)TOTS * 4);   // TOTS*4 f
constexpr size_t OFF_KEY    = AL(OFF_DELTAS + (size_t)TOTS * 16);  // NCAND u64
constexpr size_t OFF_SBOX   = AL(OFF_KEY + (size_t)NCAND * 8);     // NCAND*4 f
constexpr size_t OFF_SOB    = AL(OFF_SBOX + (size_t)NCAND * 16);   // NCAND*4 f
constexpr size_t OFF_SVAL   = AL(OFF_SOB + (size_t)NCAND * 16);    // NCAND u32
constexpr size_t OFF_MASK   = AL(OFF_SVAL + (size_t)NCAND * 4);    // ROWS_AL*WORDS u64
constexpr size_t OFF_KEEP   = AL(OFF_MASK + (size_t)ROWS_AL * WORDS * 8); // WORDS u64

// ---------------- kernel 1: weight prep ----------------
// wT[ci][ky][kx][co]  from conv_w[co][ci][ky][kx]; combined head weights/bias.
__global__ __launch_bounds__(256) void k_prep(
    const float* __restrict__ cw, const float* __restrict__ clsw,
    const float* __restrict__ clsb, const float* __restrict__ bw,
    const float* __restrict__ bb, float* __restrict__ wT,
    float* __restrict__ headw, float* __restrict__ headb) {
    int i = blockIdx.x * 256 + threadIdx.x;
    if (i < 589824) {
        int co = i & 255, r = i >> 8;
        int kx = r % 3, ky = (r / 3) % 3, ci = r / 9;
        wT[i] = cw[(((co << 8) + ci) * 3 + ky) * 3 + kx];
    }
    if (i < 3840) {
        int h = i >> 8, ci = i & 255;
        headw[i] = (h < 3) ? clsw[h * 256 + ci] : bw[(h - 3) * 256 + ci];
    }
    if (i < 15) headb[i] = (i < 3) ? clsb[i] : bb[i - 3];
}

// ---------------- kernel 2: fused conv3x3+ReLU + 1x1 heads, ALL LEVELS ----------------
// Block: 256 threads -> 8x8 pixel tile, all 256 output channels.
// Thread (cg,pg): 8 co x 8 px register micro-tile.
// LDS: single 38.5 KB staging buffer (4 blocks/CU by LDS).
// R4-EXACT REVERT. VGPR-cliff ledger (do not re-litigate):
//   r4: no prefetch            -> VGPR 128, 16 waves/CU, 1025 us  <- best
//   r5: reg-prefetch (wreg[9]) -> VGPR 164, occupancy halved, 1413 us
//   r6: global_load_lds dbuf   -> VGPR 152 (prefetch addressing), 1343 us
// Any live state added across the FMA block crosses the 128-VGPR cliff and
// loses more than the latency-hiding gains. Natural allocation + ~13 waves/CU
// TLP is the best found config for this fp32 conv.
// Also: no min-waves arg on __launch_bounds__ — (256,4)/(256,3) cap VGPRs at
// 64/84 and spill GBs to scratch (r2/r3).
__global__ __launch_bounds__(256) void k_conv(
    FeatPtrs fp, const float* __restrict__ wT,
    const float* __restrict__ convb, const float* __restrict__ headw,
    const float* __restrict__ headb, float* __restrict__ scores,
    float* __restrict__ deltas) {
    __shared__ float sm[9616];  // conv: patch[4][10][10] @0, w[9216] @400; head: part[32][196]
    const int tid = threadIdx.x;
    const int cg = tid >> 3, pg = tid & 7, co0 = cg << 3;

    // level lookup
    const int bid = blockIdx.x;
    int l = 0;
#pragma unroll
    for (int q = 1; q < 5; q++) if (bid >= cv_boff[q]) l = q;
    const int H = c_W[l], W = H;
    const int soff = c_soff[l];
    const float* __restrict__ in = fp.p[l];
    const int t = bid - cv_boff[l];
    const int tilesx = (W + 7) >> 3;
    const int tx = t % tilesx, ty = t / tilesx;
    const int x0 = tx * 8, y0 = ty * 8;
    const int HW = H * W;

    float acc[8][8];
#pragma unroll
    for (int r = 0; r < 8; r++)
#pragma unroll
        for (int c = 0; c < 8; c++) acc[r][c] = 0.f;

    for (int cc0 = 0; cc0 < 256; cc0 += 4) {
        __syncthreads();
        // patch staging (scalar, bounds-checked zero-fill)
        for (int e = tid; e < 400; e += 256) {
            int ci = e / 100, rr = e % 100, py = rr / 10, px = rr % 10;
            int gy = y0 - 1 + py, gx = x0 - 1 + px;
            float v = 0.f;
            if (gy >= 0 && gy < H && gx >= 0 && gx < W)
                v = in[(cc0 + ci) * HW + gy * W + gx];
            sm[e] = v;
        }
        // weight staging, vectorized float4 (wT 16B-aligned; sm+400 = 1600B offset, 16B-aligned)
        {
            const float4* __restrict__ wsrc4 = (const float4*)(wT + (size_t)cc0 * 2304);
            float4* smw4 = (float4*)(sm + 400);
            for (int e = tid; e < 2304; e += 256) smw4[e] = wsrc4[e];
        }
        __syncthreads();
#pragma unroll
        for (int ci = 0; ci < 4; ci++) {
#pragma unroll
            for (int ky = 0; ky < 3; ky++) {
                float in10[10];
                int prow = (ci * 10 + pg + ky) * 10;
#pragma unroll
                for (int q = 0; q < 10; q++) in10[q] = sm[prow + q];
#pragma unroll
                for (int kx = 0; kx < 3; kx++) {
                    float w8[8];
                    int wb = 400 + ((ci * 3 + ky) * 3 + kx) * 256 + co0;
#pragma unroll
                    for (int r = 0; r < 8; r++) w8[r] = sm[wb + r];
#pragma unroll
                    for (int r = 0; r < 8; r++)
#pragma unroll
                        for (int c = 0; c < 8; c++)
                            acc[r][c] = fmaf(w8[r], in10[c + kx], acc[r][c]);
                }
            }
        }
    }
    // bias + relu in registers: acc becomes t
    {
        float bias[8];
#pragma unroll
        for (int r = 0; r < 8; r++) bias[r] = convb[co0 + r];
#pragma unroll
        for (int r = 0; r < 8; r++)
#pragma unroll
            for (int c = 0; c < 8; c++) {
                float tv = acc[r][c] + bias[r];
                acc[r][c] = tv > 0.f ? tv : 0.f;
            }
    }
    // heads: 15 heads in chunks of 3; per-thread partial over its 8 co,
    // then deterministic 32-way tree over cg in LDS. part layout: [cg][px*3+h'] pad 196.
    for (int hc = 0; hc < 15; hc += 3) {
        float hw3[3][8];
#pragma unroll
        for (int h3 = 0; h3 < 3; h3++)
#pragma unroll
            for (int r = 0; r < 8; r++)
                hw3[h3][r] = headw[(hc + h3) * 256 + co0 + r];
        float part[3][8];
#pragma unroll
        for (int h3 = 0; h3 < 3; h3++)
#pragma unroll
            for (int c = 0; c < 8; c++) part[h3][c] = 0.f;
#pragma unroll
        for (int r = 0; r < 8; r++)
#pragma unroll
            for (int c = 0; c < 8; c++) {
                float tv = acc[r][c];
#pragma unroll
                for (int h3 = 0; h3 < 3; h3++)
                    part[h3][c] = fmaf(hw3[h3][r], tv, part[h3][c]);
            }
        __syncthreads();  // previous chunk's reads (or conv phase) done
        int base = cg * 196 + pg * 24;
#pragma unroll
        for (int c = 0; c < 8; c++)
#pragma unroll
            for (int h3 = 0; h3 < 3; h3++)
                sm[base + c * 3 + h3] = part[h3][c];
        __syncthreads();
        if (tid < 192) {
            int px = tid / 3, h3 = tid % 3;
            int h = hc + h3;
            float sum = 0.f;
#pragma unroll
            for (int g = 0; g < 32; g++) sum += sm[g * 196 + tid];
            sum += headb[h];
            int row = px >> 3, col = px & 7;
            int gy = y0 + row, gx = x0 + col;
            if (gy < H && gx < W) {
                int pix = gy * W + gx;
                if (h < 3) {
                    scores[soff + pix * 3 + h] = sum;
                } else {
                    int ch2 = h - 3;
                    deltas[((size_t)(soff + pix * 3 + (ch2 >> 2))) * 4 + (ch2 & 3)] = sum;
                }
            }
        }
    }
}

// ---------------- kernel 3: per-level exact top-k (radix select) ----------------
// Writes sort keys directly: key = (~flip(score) << 32) | (level<<24 | idx)
// Per-wave histograms (16x256) cut hot-bin LDS-atomic serialization ~16x.
__global__ __launch_bounds__(1024) void k_topk(
    const float* __restrict__ scores, u64* __restrict__ key) {
    const int l = blockIdx.x;
    const int Nl = c_Nl[l], off = c_soff[l], k = c_k[l];
    const int base = l * 1000;
    const int tid = threadIdx.x;
    const u32 lshift = (u32)l << 24;
    __shared__ u32 histw[16][256];
    __shared__ u32 hist[256];
    __shared__ u32 sh_prefix, sh_m, sh_sel, sh_tie;
    __shared__ u32 tiebuf[2048];
    if (tid == 0) { sh_sel = 0; sh_tie = 0; }
    __syncthreads();

    if (k == Nl) {  // take everything (level 4)
        for (int i = tid; i < Nl; i += 1024) {
            u32 p = atomicAdd(&sh_sel, 1u);
            u32 k32 = flipf(scores[off + i]);
            key[base + p] = ((u64)(~k32) << 32) | (u64)(lshift | (u32)i);
        }
        return;
    }
    const int wid = tid >> 6;
    u32 prefix = 0, m = (u32)k;
    for (int p = 0; p < 4; p++) {
        int shift = 24 - 8 * p;
        for (int b = tid; b < 4096; b += 1024) ((u32*)histw)[b] = 0;
        __syncthreads();
        for (int i = tid; i < Nl; i += 1024) {
            u32 k32 = flipf(scores[off + i]);
            if (p == 0 || (k32 >> (shift + 8)) == prefix)
                atomicAdd(&histw[wid][(k32 >> shift) & 255u], 1u);
        }
        __syncthreads();
        for (int b = tid; b < 256; b += 1024) {
            u32 s = 0;
#pragma unroll
            for (int w = 0; w < 16; w++) s += histw[w][b];
            hist[b] = s;
        }
        __syncthreads();
        if (tid == 0) {
            u32 cum = 0;
            for (int b = 255; b >= 0; --b) {
                u32 c = hist[b];
                if (cum + c >= m) { sh_prefix = (prefix << 8) | (u32)b; sh_m = m - cum; break; }
                cum += c;
            }
        }
        __syncthreads();
        prefix = sh_prefix; m = sh_m;
        __syncthreads();
    }
    // compact: strictly greater -> selected; equal -> tie list
    for (int i = tid; i < Nl; i += 1024) {
        u32 k32 = flipf(scores[off + i]);
        if (k32 > prefix) {
            u32 p = atomicAdd(&sh_sel, 1u);
            key[base + p] = ((u64)(~k32) << 32) | (u64)(lshift | (u32)i);
        } else if (k32 == prefix) {
            u32 t = atomicAdd(&sh_tie, 1u);
            if (t < 2048u) tiebuf[t] = (u32)i;
        }
    }
    __syncthreads();
    u32 nsel = sh_sel;
    u32 ntie = sh_tie; if (ntie > 2048u) ntie = 2048u;
    if (ntie != m) {  // need m smallest indices among ties
        for (u32 j = tid; j < 2048; j += 1024) if (j >= ntie) tiebuf[j] = 0xFFFFFFFFu;
        __syncthreads();
        for (u32 ksz = 2; ksz <= 2048; ksz <<= 1) {
            for (u32 jj = ksz >> 1; jj > 0; jj >>= 1) {
                for (u32 i2 = tid; i2 < 2048; i2 += 1024) {
                    u32 ixj = i2 ^ jj;
                    if (ixj > i2) {
                        u32 a = tiebuf[i2], b = tiebuf[ixj];
                        bool up = ((i2 & ksz) == 0);
                        if ((a > b) == up) { tiebuf[i2] = b; tiebuf[ixj] = a; }
                    }
                }
                __syncthreads();
            }
        }
    }
    for (u32 j = tid; j < m; j += 1024)
        key[base + nsel + j] = ((u64)(~prefix) << 32) | (u64)(lshift | tiebuf[j]);
}

// ---------------- kernel 4: global bitonic sort + inline decode ----------------
__global__ __launch_bounds__(1024) void k_sort(
    const u64* __restrict__ key, const float* __restrict__ deltas, DecParams P,
    float* __restrict__ sboxes, float* __restrict__ sob, u32* __restrict__ svalid) {
    __shared__ u64 sk[8192];
    const int tid = threadIdx.x;
    for (int i = tid; i < 8192; i += 1024) sk[i] = (i < NCAND) ? key[i] : ~0ull;
    __syncthreads();
    for (u32 ksz = 2; ksz <= 8192; ksz <<= 1) {
        for (u32 j = ksz >> 1; j > 0; j >>= 1) {
            for (u32 i = tid; i < 8192; i += 1024) {
                u32 ixj = i ^ j;
                if (ixj > i) {
                    u64 a = sk[i], b = sk[ixj];
                    bool up = ((i & ksz) == 0);
                    if ((a > b) == up) { sk[i] = b; sk[ixj] = a; }
                }
            }
            __syncthreads();
        }
    }
    const float CLAMP = 4.135166556742356f;  // log(1000/16)
    for (int s = tid; s < NCAND; s += 1024) {
        u32 info = (u32)sk[s];
        int l = info >> 24, idx = info & 0xFFFFFF;
        int W = c_W[l], st = c_stride[l];
        int a = idx % 3, pix = idx / 3;
        int x = pix % W, y = pix / W;
        float ax1 = x * st + P.b[l][a][0];
        float ay1 = y * st + P.b[l][a][1];
        float ax2 = x * st + P.b[l][a][2];
        float ay2 = y * st + P.b[l][a][3];
        float w_ = ax2 - ax1, h_ = ay2 - ay1;
        float cx = ax1 + 0.5f * w_, cy = ay1 + 0.5f * h_;
        const float* d = deltas + ((size_t)(c_soff[l] + idx)) * 4;
        float dx = d[0], dy = d[1];
        float dw = fminf(d[2], CLAMP), dh = fminf(d[3], CLAMP);
        float pcx = dx * w_ + cx, pcy = dy * h_ + cy;
        float pw = expf(dw) * w_, ph = expf(dh) * h_;
        float x1 = pcx - 0.5f * pw, y1 = pcy - 0.5f * ph;
        float x2 = pcx + 0.5f * pw, y2 = pcy + 0.5f * ph;
        x1 = fminf(fmaxf(x1, 0.f), 800.f); y1 = fminf(fmaxf(y1, 0.f), 800.f);
        x2 = fminf(fmaxf(x2, 0.f), 800.f); y2 = fminf(fmaxf(y2, 0.f), 800.f);
        u32 vv = (x2 - x1 >= 0.001f && y2 - y1 >= 0.001f) ? 1u : 0u;
        float offv = (float)l * 801.0f;
        sboxes[s * 4 + 0] = x1; sboxes[s * 4 + 1] = y1;
        sboxes[s * 4 + 2] = x2; sboxes[s * 4 + 3] = y2;
        sob[s * 4 + 0] = x1 + offv; sob[s * 4 + 1] = y1 + offv;
        sob[s * 4 + 2] = x2 + offv; sob[s * 4 + 3] = y2 + offv;
        svalid[s] = vv;
    }
}

// ---------------- kernel 5: IoU suppression bitmask ----------------
__global__ __launch_bounds__(256) void k_mask(
    const float* __restrict__ sob, u64* __restrict__ mask) {
    int gid = blockIdx.x * 256 + threadIdx.x;
    const int total = NCAND * WORDS;
    if (gid >= total) return;
    int i = gid / WORDS, w = gid - i * WORDS;
    float bx1 = sob[i * 4], by1 = sob[i * 4 + 1], bx2 = sob[i * 4 + 2], by2 = sob[i * 4 + 3];
    float ai = (bx2 - bx1) * (by2 - by1);
    u64 bits = 0;
    int j0 = w * 64;
    for (int b = 0; b < 64; b++) {
        int j = j0 + b;
        if (j < NCAND && j > i) {
            float cx1 = sob[j * 4], cy1 = sob[j * 4 + 1], cx2 = sob[j * 4 + 2], cy2 = sob[j * 4 + 3];
            float lt0 = fmaxf(bx1, cx1), lt1 = fmaxf(by1, cy1);
            float rb0 = fminf(bx2, cx2), rb1 = fminf(by2, cy2);
            float ww = fmaxf(rb0 - lt0, 0.f), hh = fmaxf(rb1 - lt1, 0.f);
            float inter = ww * hh;
            float aj = (cx2 - cx1) * (cy2 - cy1);
            float u = ai + aj - inter;
            float iou = inter / u;           // 0/0 -> NaN -> no suppression (matches ref)
            if (iou > 0.7f) bits |= (1ull << b);
        }
    }
    mask[(size_t)i * WORDS + w] = bits;
}

// ---------------- kernel 6: tiled greedy NMS scan (single block, 1024 thr) ----------------
__global__ __launch_bounds__(1024) void k_scan(
    const u64* __restrict__ mask, const u32* __restrict__ svalid,
    u64* __restrict__ keepg) {
    __shared__ u64 keep[WORDS];
    __shared__ u32 ormL[WORDS], ormH[WORDS];
    const int tid = threadIdx.x;
    if (tid < WORDS) {
        u64 w0 = 0;
        for (int b = 0; b < 64; b++) {
            int idx = tid * 64 + b;
            if (idx < NCAND && svalid[idx]) w0 |= (1ull << b);
        }
        keep[tid] = w0; ormL[tid] = 0; ormH[tid] = 0;
    }
    __syncthreads();
    for (int t = 0; t < WORDS; t++) {
        if (tid < 64) {  // wave 0: serial intra-tile resolve on the diagonal word
            int row = t * 64 + tid;
            u64 d = (row < NCAND) ? mask[(size_t)row * WORDS + t] : 0ull;
            u32 dlo = (u32)d, dhi = (u32)(d >> 32);
            u64 cur = keep[t];
            u64 pending = cur;
            while (pending) {
                int b = __builtin_ctzll(pending);
                pending &= pending - 1;
                u64 mb = ((u64)__shfl(dhi, b, 64) << 32) | (u64)__shfl(dlo, b, 64);
                cur &= ~mb;       // row b is alive (pending only holds survivors)
                pending &= ~mb;   // skip rows it just suppressed
            }
            if (tid == 0) keep[t] = cur;
        }
        __syncthreads();
        u64 kw = keep[t];
        int nW = WORDS - 1 - t;
        for (int task = tid; task < 64 * nW; task += 1024) {
            int r = task / nW, w = t + 1 + (task - r * nW);
            if ((kw >> r) & 1ull) {
                u64 mrow = mask[(size_t)(t * 64 + r) * WORDS + w];
                if (mrow) {
                    atomicOr(&ormL[w], (u32)mrow);
                    atomicOr(&ormH[w], (u32)(mrow >> 32));
                }
            }
        }
        __syncthreads();
        if (tid > t && tid < WORDS) {
            keep[tid] &= ~(((u64)ormH[tid] << 32) | (u64)ormL[tid]);
            ormL[tid] = 0; ormH[tid] = 0;
        }
        __syncthreads();
    }
    if (tid < WORDS) keepg[tid] = keep[tid];
}

// ---------------- kernel 7: final gather (kept first, then suppressed in index order) ----------------
__global__ __launch_bounds__(1024) void k_out(
    const u64* __restrict__ keepg, const float* __restrict__ sboxes,
    float* __restrict__ out) {
    __shared__ u32 sc[1024];
    __shared__ u64 kw[WORDS];
    const int tid = threadIdx.x;
    if (tid < WORDS) kw[tid] = keepg[tid];
    __syncthreads();
    const int i0 = tid * 5;
    u32 cnt = 0;
    for (int e = 0; e < 5; e++) {
        int i = i0 + e;
        if (i < NCAND) cnt += (u32)((kw[i >> 6] >> (i & 63)) & 1ull);
    }
    sc[tid] = cnt;
    __syncthreads();
    for (int off = 1; off < 1024; off <<= 1) {
        u32 v = (tid >= off) ? sc[tid - off] : 0;
        __syncthreads();
        sc[tid] += v;
        __syncthreads();
    }
    u32 incl = sc[tid];
    u32 total = sc[1023];
    u32 kr = incl - cnt;  // kept before my first element
    for (int e = 0; e < 5; e++) {
        int i = i0 + e;
        if (i < NCAND) {
            bool kp = (kw[i >> 6] >> (i & 63)) & 1ull;
            if (kp) {
                if (kr < 1000u) {
                    out[kr * 4 + 0] = sboxes[i * 4 + 0];
                    out[kr * 4 + 1] = sboxes[i * 4 + 1];
                    out[kr * 4 + 2] = sboxes[i * 4 + 2];
                    out[kr * 4 + 3] = sboxes[i * 4 + 3];
                }
                kr++;
            } else {
                u32 slot = total + (u32)i - kr;
                if (slot < 1000u) {
                    out[slot * 4 + 0] = sboxes[i * 4 + 0];
                    out[slot * 4 + 1] = sboxes[i * 4 + 1];
                    out[slot * 4 + 2] = sboxes[i * 4 + 2];
                    out[slot * 4 + 3] = sboxes[i * 4 + 3];
                }
            }
        }
    }
}

// ---------------- host ----------------
extern "C" void kernel_launch(void* const* d_in, const int* in_sizes, int n_in,
                              void* d_out, int out_size, void* d_ws, size_t ws_size,
                              hipStream_t stream) {
    (void)in_sizes; (void)n_in; (void)out_size; (void)ws_size;
    FeatPtrs fp;
    for (int i = 0; i < 5; i++) fp.p[i] = (const float*)d_in[i];
    const float* conv_w = (const float*)d_in[5];
    const float* conv_b = (const float*)d_in[6];
    const float* cls_w  = (const float*)d_in[7];
    const float* cls_b  = (const float*)d_in[8];
    const float* bbox_w = (const float*)d_in[9];
    const float* bbox_b = (const float*)d_in[10];

    char* ws = (char*)d_ws;
    float* wT     = (float*)(ws + OFF_WT);
    float* headw  = (float*)(ws + OFF_HEADW);
    float* headb  = (float*)(ws + OFF_HEADB);
    float* scores = (float*)(ws + OFF_SCORES);
    float* deltas = (float*)(ws + OFF_DELTAS);
    u64*   key    = (u64*)(ws + OFF_KEY);
    float* sboxes = (float*)(ws + OFF_SBOX);
    float* sob    = (float*)(ws + OFF_SOB);
    u32*   svalid = (u32*)(ws + OFF_SVAL);
    u64*   maskp  = (u64*)(ws + OFF_MASK);
    u64*   keepg  = (u64*)(ws + OFF_KEEP);

    k_prep<<<2304, 256, 0, stream>>>(conv_w, cls_w, cls_b, bbox_w, bbox_b, wT, headw, headb);

    // one launch for all 5 levels: 625+169+49+16+4 = 863 tiles
    k_conv<<<863, 256, 0, stream>>>(fp, wT, conv_b, headw, headb, scores, deltas);

    k_topk<<<5, 1024, 0, stream>>>(scores, key);

    DecParams dp;
    {
        const double sz[5] = {32.0, 64.0, 128.0, 256.0, 512.0};
        const double rt[3] = {0.5, 1.0, 2.0};
        for (int l = 0; l < 5; l++)
            for (int a = 0; a < 3; a++) {
                double hr = sqrt(rt[a]);
                double wr = 1.0 / hr;
                double w = wr * sz[l], h = hr * sz[l];
                dp.b[l][a][0] = (float)nearbyint(-w / 2.0);
                dp.b[l][a][1] = (float)nearbyint(-h / 2.0);
                dp.b[l][a][2] = (float)nearbyint(w / 2.0);
                dp.b[l][a][3] = (float)nearbyint(h / 2.0);
            }
    }
    k_sort<<<1, 1024, 0, stream>>>(key, deltas, dp, sboxes, sob, svalid);
    k_mask<<<(NCAND * WORDS + 255) / 256, 256, 0, stream>>>(sob, maskp);
    k_scan<<<1, 1024, 0, stream>>>(maskp, svalid, keepg);
    k_out<<<1, 1024, 0, stream>>>(keepg, sboxes, (float*)d_out);
}

// Round 8
// 1166.288 us; speedup vs baseline: 1.7145x; 1.3302x over previous
//
#include <hip/hip_runtime.h>
#include <cmath>

typedef unsigned int u32;
typedef unsigned long long u64;
typedef _Float16 f16;
typedef _Float16 f16x8 __attribute__((ext_vector_type(8)));
typedef float f32x4 __attribute__((ext_vector_type(4)));

// address-space-qualified typedefs for global_load_lds
typedef __attribute__((address_space(1))) const unsigned int gu32;
typedef __attribute__((address_space(3))) unsigned int lu32;

#define NCAND 4507
#define WORDS 71              // ceil(4507/64)
#define ROWS_AL (WORDS * 64)  // 4544
#define TOTS 159882           // total scores across levels

__constant__ int c_W[5]      = {200, 100, 50, 25, 13};
__constant__ int c_stride[5] = {4, 8, 16, 32, 61};
__constant__ int c_Nl[5]     = {120000, 30000, 7500, 1875, 507};
__constant__ int c_soff[5]   = {0, 120000, 150000, 157500, 159375};
__constant__ int c_k[5]      = {1000, 1000, 1000, 1000, 507};

// unified conv grid: tiles per level (8x8 px tiles): 625,169,49,16,4
__constant__ int cv_boff[6]  = {0, 625, 794, 843, 859, 863};

struct DecParams { float b[5][3][4]; };
struct FeatPtrs { const float* p[5]; };

__device__ __forceinline__ u32 flipf(float f) {
    u32 u = __float_as_uint(f);
    return (u & 0x80000000u) ? ~u : (u | 0x80000000u);
}

// ---------------- workspace layout ----------------
constexpr size_t AL(size_t x) { return (x + 255) & ~(size_t)255; }
constexpr size_t OFF_WHI    = 0;                                   // 72*16KB f16
constexpr size_t OFF_WLO    = AL(OFF_WHI + 1179648);
constexpr size_t OFF_HEADW  = AL(OFF_WLO + 1179648);               // 15*256 f
constexpr size_t OFF_HEADB  = AL(OFF_HEADW + 3840 * 4);            // 15 f
constexpr size_t OFF_SCORES = AL(OFF_HEADB + 64);                  // TOTS f
constexpr size_t OFF_DELTAS = AL(OFF_SCORES + (size_t)TOTS * 4);   // TOTS*4 f
constexpr size_t OFF_KEY    = AL(OFF_DELTAS + (size_t)TOTS * 16);  // NCAND u64
constexpr size_t OFF_SBOX   = AL(OFF_KEY + (size_t)NCAND * 8);     // NCAND*4 f
constexpr size_t OFF_SOB    = AL(OFF_SBOX + (size_t)NCAND * 16);   // NCAND*4 f
constexpr size_t OFF_SVAL   = AL(OFF_SOB + (size_t)NCAND * 16);    // NCAND u32
constexpr size_t OFF_MASK   = AL(OFF_SVAL + (size_t)NCAND * 4);    // ROWS_AL*WORDS u64
constexpr size_t OFF_KEEP   = AL(OFF_MASK + (size_t)ROWS_AL * WORDS * 8); // WORDS u64

// ---------------- kernel 1: weight prep ----------------
// fp16 hi/lo split of conv weights into MFMA-B layout:
//   block (chunk=ci>>5, kk=ky*3+kx) of 16KB; within block, element (co, cir=ci&31)
//   at f16-index co*32 + ((cir>>3) ^ ((co>>1)&3))*8 + (cir&7)   [XOR bank swizzle]
// lo parts scaled by 2^11 (raw lo of w~0.02 is f16-subnormal; robust to denorm flush).
__global__ __launch_bounds__(256) void k_prep(
    const float* __restrict__ cw, const float* __restrict__ clsw,
    const float* __restrict__ clsb, const float* __restrict__ bw,
    const float* __restrict__ bb, f16* __restrict__ whi, f16* __restrict__ wlo,
    float* __restrict__ headw, float* __restrict__ headb) {
    int i = blockIdx.x * 256 + threadIdx.x;
    if (i < 589824) {
        int kx = i % 3, t1 = i / 3;
        int ky = t1 % 3, t2 = t1 / 3;
        int ci = t2 & 255, co = t2 >> 8;
        float w = cw[i];
        f16 hi = (f16)w;
        f16 lo = (f16)((w - (float)hi) * 2048.0f);
        int chunk = ci >> 5, cir = ci & 31, kk = ky * 3 + kx;
        size_t blk = (size_t)(chunk * 9 + kk) * 8192;
        int within = co * 32 + (((cir >> 3) ^ ((co >> 1) & 3)) << 3) + (cir & 7);
        whi[blk + within] = hi;
        wlo[blk + within] = lo;
    }
    if (i < 3840) {
        int h = i >> 8, ci = i & 255;
        headw[i] = (h < 3) ? clsw[h * 256 + ci] : bw[(h - 3) * 256 + ci];
    }
    if (i < 15) headb[i] = (i < 3) ? clsb[i] : bb[i - 3];
}

// ---------------- kernel 2: MFMA fp16-split conv3x3+ReLU + 1x1 heads ----------------
// Implicit GEMM per block: M=64 px (8x8 tile), N=256 co, K=2304 (8 ci-chunks x 9 taps x 32).
// Each wave: all 64 px x its 64 co -> acc 4x4 frags x2 (main + scaled-cross).
// D = acc1 + acc2 * 2^-11  (3-pass split: hh -> acc1; h*lo' + lo'*h -> acc2, lo' = lo*2^11).
// A: channel-last fp16 patch [10][10][32] in LDS (contiguous b128 frags, ~2-way banks).
// B: pre-swizzled global blocks, double-buffered via global_load_lds (linear dest).
// LDS = A(2x6400) + B(2x32KB) = 78336 B -> 2 blocks/CU; VGPR ~200 (<256, no cliff).
// Fragment layout assumed: A row=lane&15, k=(lane>>4)*8+j; B symmetric; D col=lane&15,
// row=(lane>>4)*4+reg [m89-verified]. Go/no-go: absmax.
__global__ __launch_bounds__(256) void k_conv(
    FeatPtrs fp, const f16* __restrict__ whi, const f16* __restrict__ wlo,
    const float* __restrict__ convb, const float* __restrict__ headw,
    const float* __restrict__ headb, float* __restrict__ scores,
    float* __restrict__ deltas) {
    __shared__ float4 smq[4896];  // 78336 B
    char* smb = (char*)smq;
    const int tid = threadIdx.x;
    const int lane = tid & 63, wv = tid >> 6;
    const int l15 = lane & 15, l4 = lane >> 4;

    // level lookup
    const int bid = blockIdx.x;
    int l = 0;
#pragma unroll
    for (int q = 1; q < 5; q++) if (bid >= cv_boff[q]) l = q;
    const int H = c_W[l], W = H;
    const int soff = c_soff[l];
    const float* __restrict__ in = fp.p[l];
    const int t = bid - cv_boff[l];
    const int tilesx = (W + 7) >> 3;
    const int tx = t % tilesx, ty = t / tilesx;
    const int x0 = tx * 8, y0 = ty * 8;
    const int HW = H * W;

    // A-fragment base byte offsets (per M-tile), within patch buffer
    int abase[4];
#pragma unroll
    for (int mt = 0; mt < 4; mt++) {
        int r = mt * 2 + (l15 >> 3), c = lane & 7;
        abase[mt] = (r * 10 + c) * 64 + l4 * 16;
    }
    // B-fragment offsets (per N-tile) within a 16KB hi/lo block (XOR swizzle)
    int bco[4], boff[4];
#pragma unroll
    for (int nt = 0; nt < 4; nt++) {
        int co = wv * 64 + nt * 16 + l15;
        bco[nt] = co;
        boff[nt] = co * 64 + ((l4 ^ ((co >> 1) & 3)) << 4);
    }

    f32x4 acc1[4][4], acc2[4][4];
#pragma unroll
    for (int mt = 0; mt < 4; mt++)
#pragma unroll
        for (int nt = 0; nt < 4; nt++) {
            acc1[mt][nt] = (f32x4)0.0f;
            acc2[mt][nt] = (f32x4)0.0f;
        }

    // stage channel-last fp16 patch (hi @0, scaled-lo @6400) for ci-chunk c
    auto stagePatch = [&](int chunk) {
        const int c0 = chunk << 5;
        f16* ph = (f16*)smb;
        f16* pl = (f16*)(smb + 6400);
        for (int e = tid; e < 3200; e += 256) {
            int py = e / 320, rem = e - py * 320;
            int px = rem >> 5, ci = rem & 31;
            int gy = y0 - 1 + py, gx = x0 - 1 + px;
            float v = 0.f;
            if (gy >= 0 && gy < H && gx >= 0 && gx < W)
                v = in[(c0 + ci) * HW + gy * W + gx];
            f16 hi = (f16)v;
            ph[e] = hi;
            pl[e] = (f16)((v - (float)hi) * 2048.0f);
        }
    };
    // async-stage B block sidx into buffer buf (hi 16KB + lo 16KB), linear dest
    auto issueB = [&](int sidx, int buf) {
        const char* gh = (const char*)whi + (size_t)sidx * 16384;
        const char* gl = (const char*)wlo + (size_t)sidx * 16384;
        char* dh = smb + 12800 + buf * 32768;
        char* dl = dh + 16384;
#pragma unroll
        for (int q = 0; q < 4; q++) {
            int i1 = (wv * 4 + q) * 1024;
            __builtin_amdgcn_global_load_lds((gu32*)(gh + i1 + lane * 16), (lu32*)(dh + i1), 16, 0, 0);
            __builtin_amdgcn_global_load_lds((gu32*)(gl + i1 + lane * 16), (lu32*)(dl + i1), 16, 0, 0);
        }
    };

    stagePatch(0);
    issueB(0, 0);
    __syncthreads();

    int kk = 0, chunk = 0;
    for (int s = 0; s < 72; ++s) {
        const int buf = s & 1;
        if (s < 71) issueB(s + 1, buf ^ 1);
        {
            const int ky = kk / 3, kx = kk - ky * 3;
            const int aoff = (ky * 10 + kx) * 64;
            const char* bh = smb + 12800 + buf * 32768;
            const char* bl = bh + 16384;
            f16x8 ah[4], al[4];
#pragma unroll
            for (int mt = 0; mt < 4; mt++) {
                ah[mt] = *(const f16x8*)(smb + abase[mt] + aoff);
                al[mt] = *(const f16x8*)(smb + 6400 + abase[mt] + aoff);
            }
#pragma unroll
            for (int nt = 0; nt < 4; nt++) {
                f16x8 vbh = *(const f16x8*)(bh + boff[nt]);
                f16x8 vbl = *(const f16x8*)(bl + boff[nt]);
#pragma unroll
                for (int mt = 0; mt < 4; mt++) {
                    acc1[mt][nt] = __builtin_amdgcn_mfma_f32_16x16x32_f16(ah[mt], vbh, acc1[mt][nt], 0, 0, 0);
                    acc2[mt][nt] = __builtin_amdgcn_mfma_f32_16x16x32_f16(ah[mt], vbl, acc2[mt][nt], 0, 0, 0);
                    acc2[mt][nt] = __builtin_amdgcn_mfma_f32_16x16x32_f16(al[mt], vbh, acc2[mt][nt], 0, 0, 0);
                }
            }
        }
        if (kk == 8) {
            kk = 0; chunk++;
            if (chunk < 8) { __syncthreads(); stagePatch(chunk); }
        } else kk++;
        __syncthreads();
    }

    // epilogue: combine split, + bias, ReLU -> t in acc1
    const float INV2048 = 4.8828125e-4f;
    {
        float cb[4];
#pragma unroll
        for (int nt = 0; nt < 4; nt++) cb[nt] = convb[bco[nt]];
#pragma unroll
        for (int mt = 0; mt < 4; mt++)
#pragma unroll
            for (int nt = 0; nt < 4; nt++)
#pragma unroll
                for (int r = 0; r < 4; r++) {
                    float tv = acc1[mt][nt][r] + acc2[mt][nt][r] * INV2048 + cb[nt];
                    acc1[mt][nt][r] = tv > 0.f ? tv : 0.f;
                }
    }

    // heads: per thread partial over its 4 co (one per N-tile) for each of its 16 px slots,
    // shfl_xor butterfly over the 16 col-lanes, cross-wave sum via LDS (fixed order).
    float* part = (float*)smb;  // [4 wv][64 px][3]
    for (int hc = 0; hc < 15; hc += 3) {
        float hw3[3][4];
#pragma unroll
        for (int h3 = 0; h3 < 3; h3++)
#pragma unroll
            for (int nt = 0; nt < 4; nt++)
                hw3[h3][nt] = headw[(hc + h3) * 256 + bco[nt]];
#pragma unroll
        for (int mt = 0; mt < 4; mt++)
#pragma unroll
            for (int r = 0; r < 4; r++) {
                float p0 = 0.f, p1 = 0.f, p2 = 0.f;
#pragma unroll
                for (int nt = 0; nt < 4; nt++) {
                    float tv = acc1[mt][nt][r];
                    p0 = fmaf(hw3[0][nt], tv, p0);
                    p1 = fmaf(hw3[1][nt], tv, p1);
                    p2 = fmaf(hw3[2][nt], tv, p2);
                }
                p0 += __shfl_xor(p0, 1); p0 += __shfl_xor(p0, 2); p0 += __shfl_xor(p0, 4); p0 += __shfl_xor(p0, 8);
                p1 += __shfl_xor(p1, 1); p1 += __shfl_xor(p1, 2); p1 += __shfl_xor(p1, 4); p1 += __shfl_xor(p1, 8);
                p2 += __shfl_xor(p2, 1); p2 += __shfl_xor(p2, 2); p2 += __shfl_xor(p2, 4); p2 += __shfl_xor(p2, 8);
                if (l15 == 0) {
                    int px = mt * 16 + l4 * 4 + r;
                    part[(wv * 64 + px) * 3 + 0] = p0;
                    part[(wv * 64 + px) * 3 + 1] = p1;
                    part[(wv * 64 + px) * 3 + 2] = p2;
                }
            }
        __syncthreads();
        if (tid < 192) {
            int px = tid / 3, h3 = tid % 3;
            int h = hc + h3;
            float sum = part[px * 3 + h3] + part[(64 + px) * 3 + h3] +
                        part[(128 + px) * 3 + h3] + part[(192 + px) * 3 + h3];
            sum += headb[h];
            int gy = y0 + (px >> 3), gx = x0 + (px & 7);
            if (gy < H && gx < W) {
                int pix = gy * W + gx;
                if (h < 3) {
                    scores[soff + pix * 3 + h] = sum;
                } else {
                    int ch2 = h - 3;
                    deltas[((size_t)(soff + pix * 3 + (ch2 >> 2))) * 4 + (ch2 & 3)] = sum;
                }
            }
        }
        __syncthreads();
    }
}

// ---------------- kernel 3: per-level exact top-k (radix select) ----------------
__global__ __launch_bounds__(1024) void k_topk(
    const float* __restrict__ scores, u64* __restrict__ key) {
    const int l = blockIdx.x;
    const int Nl = c_Nl[l], off = c_soff[l], k = c_k[l];
    const int base = l * 1000;
    const int tid = threadIdx.x;
    const u32 lshift = (u32)l << 24;
    __shared__ u32 histw[16][256];
    __shared__ u32 hist[256];
    __shared__ u32 sh_prefix, sh_m, sh_sel, sh_tie;
    __shared__ u32 tiebuf[2048];
    if (tid == 0) { sh_sel = 0; sh_tie = 0; }
    __syncthreads();

    if (k == Nl) {
        for (int i = tid; i < Nl; i += 1024) {
            u32 p = atomicAdd(&sh_sel, 1u);
            u32 k32 = flipf(scores[off + i]);
            key[base + p] = ((u64)(~k32) << 32) | (u64)(lshift | (u32)i);
        }
        return;
    }
    const int wid = tid >> 6;
    u32 prefix = 0, m = (u32)k;
    for (int p = 0; p < 4; p++) {
        int shift = 24 - 8 * p;
        for (int b = tid; b < 4096; b += 1024) ((u32*)histw)[b] = 0;
        __syncthreads();
        for (int i = tid; i < Nl; i += 1024) {
            u32 k32 = flipf(scores[off + i]);
            if (p == 0 || (k32 >> (shift + 8)) == prefix)
                atomicAdd(&histw[wid][(k32 >> shift) & 255u], 1u);
        }
        __syncthreads();
        for (int b = tid; b < 256; b += 1024) {
            u32 s = 0;
#pragma unroll
            for (int w = 0; w < 16; w++) s += histw[w][b];
            hist[b] = s;
        }
        __syncthreads();
        if (tid == 0) {
            u32 cum = 0;
            for (int b = 255; b >= 0; --b) {
                u32 c = hist[b];
                if (cum + c >= m) { sh_prefix = (prefix << 8) | (u32)b; sh_m = m - cum; break; }
                cum += c;
            }
        }
        __syncthreads();
        prefix = sh_prefix; m = sh_m;
        __syncthreads();
    }
    for (int i = tid; i < Nl; i += 1024) {
        u32 k32 = flipf(scores[off + i]);
        if (k32 > prefix) {
            u32 p = atomicAdd(&sh_sel, 1u);
            key[base + p] = ((u64)(~k32) << 32) | (u64)(lshift | (u32)i);
        } else if (k32 == prefix) {
            u32 t = atomicAdd(&sh_tie, 1u);
            if (t < 2048u) tiebuf[t] = (u32)i;
        }
    }
    __syncthreads();
    u32 nsel = sh_sel;
    u32 ntie = sh_tie; if (ntie > 2048u) ntie = 2048u;
    if (ntie != m) {
        for (u32 j = tid; j < 2048; j += 1024) if (j >= ntie) tiebuf[j] = 0xFFFFFFFFu;
        __syncthreads();
        for (u32 ksz = 2; ksz <= 2048; ksz <<= 1) {
            for (u32 jj = ksz >> 1; jj > 0; jj >>= 1) {
                for (u32 i2 = tid; i2 < 2048; i2 += 1024) {
                    u32 ixj = i2 ^ jj;
                    if (ixj > i2) {
                        u32 a = tiebuf[i2], b = tiebuf[ixj];
                        bool up = ((i2 & ksz) == 0);
                        if ((a > b) == up) { tiebuf[i2] = b; tiebuf[ixj] = a; }
                    }
                }
                __syncthreads();
            }
        }
    }
    for (u32 j = tid; j < m; j += 1024)
        key[base + nsel + j] = ((u64)(~prefix) << 32) | (u64)(lshift | tiebuf[j]);
}

// ---------------- kernel 4: global bitonic sort + inline decode ----------------
__global__ __launch_bounds__(1024) void k_sort(
    const u64* __restrict__ key, const float* __restrict__ deltas, DecParams P,
    float* __restrict__ sboxes, float* __restrict__ sob, u32* __restrict__ svalid) {
    __shared__ u64 sk[8192];
    const int tid = threadIdx.x;
    for (int i = tid; i < 8192; i += 1024) sk[i] = (i < NCAND) ? key[i] : ~0ull;
    __syncthreads();
    for (u32 ksz = 2; ksz <= 8192; ksz <<= 1) {
        for (u32 j = ksz >> 1; j > 0; j >>= 1) {
            for (u32 i = tid; i < 8192; i += 1024) {
                u32 ixj = i ^ j;
                if (ixj > i) {
                    u64 a = sk[i], b = sk[ixj];
                    bool up = ((i & ksz) == 0);
                    if ((a > b) == up) { sk[i] = b; sk[ixj] = a; }
                }
            }
            __syncthreads();
        }
    }
    const float CLAMP = 4.135166556742356f;
    for (int s = tid; s < NCAND; s += 1024) {
        u32 info = (u32)sk[s];
        int l = info >> 24, idx = info & 0xFFFFFF;
        int W = c_W[l], st = c_stride[l];
        int a = idx % 3, pix = idx / 3;
        int x = pix % W, y = pix / W;
        float ax1 = x * st + P.b[l][a][0];
        float ay1 = y * st + P.b[l][a][1];
        float ax2 = x * st + P.b[l][a][2];
        float ay2 = y * st + P.b[l][a][3];
        float w_ = ax2 - ax1, h_ = ay2 - ay1;
        float cx = ax1 + 0.5f * w_, cy = ay1 + 0.5f * h_;
        const float* d = deltas + ((size_t)(c_soff[l] + idx)) * 4;
        float dx = d[0], dy = d[1];
        float dw = fminf(d[2], CLAMP), dh = fminf(d[3], CLAMP);
        float pcx = dx * w_ + cx, pcy = dy * h_ + cy;
        float pw = expf(dw) * w_, ph = expf(dh) * h_;
        float x1 = pcx - 0.5f * pw, y1 = pcy - 0.5f * ph;
        float x2 = pcx + 0.5f * pw, y2 = pcy + 0.5f * ph;
        x1 = fminf(fmaxf(x1, 0.f), 800.f); y1 = fminf(fmaxf(y1, 0.f), 800.f);
        x2 = fminf(fmaxf(x2, 0.f), 800.f); y2 = fminf(fmaxf(y2, 0.f), 800.f);
        u32 vv = (x2 - x1 >= 0.001f && y2 - y1 >= 0.001f) ? 1u : 0u;
        float offv = (float)l * 801.0f;
        sboxes[s * 4 + 0] = x1; sboxes[s * 4 + 1] = y1;
        sboxes[s * 4 + 2] = x2; sboxes[s * 4 + 3] = y2;
        sob[s * 4 + 0] = x1 + offv; sob[s * 4 + 1] = y1 + offv;
        sob[s * 4 + 2] = x2 + offv; sob[s * 4 + 3] = y2 + offv;
        svalid[s] = vv;
    }
}

// ---------------- kernel 5: IoU suppression bitmask ----------------
__global__ __launch_bounds__(256) void k_mask(
    const float* __restrict__ sob, u64* __restrict__ mask) {
    int gid = blockIdx.x * 256 + threadIdx.x;
    const int total = NCAND * WORDS;
    if (gid >= total) return;
    int i = gid / WORDS, w = gid - i * WORDS;
    float bx1 = sob[i * 4], by1 = sob[i * 4 + 1], bx2 = sob[i * 4 + 2], by2 = sob[i * 4 + 3];
    float ai = (bx2 - bx1) * (by2 - by1);
    u64 bits = 0;
    int j0 = w * 64;
    for (int b = 0; b < 64; b++) {
        int j = j0 + b;
        if (j < NCAND && j > i) {
            float cx1 = sob[j * 4], cy1 = sob[j * 4 + 1], cx2 = sob[j * 4 + 2], cy2 = sob[j * 4 + 3];
            float lt0 = fmaxf(bx1, cx1), lt1 = fmaxf(by1, cy1);
            float rb0 = fminf(bx2, cx2), rb1 = fminf(by2, cy2);
            float ww = fmaxf(rb0 - lt0, 0.f), hh = fmaxf(rb1 - lt1, 0.f);
            float inter = ww * hh;
            float aj = (cx2 - cx1) * (cy2 - cy1);
            float u = ai + aj - inter;
            float iou = inter / u;
            if (iou > 0.7f) bits |= (1ull << b);
        }
    }
    mask[(size_t)i * WORDS + w] = bits;
}

// ---------------- kernel 6: tiled greedy NMS scan (single block, 1024 thr) ----------------
__global__ __launch_bounds__(1024) void k_scan(
    const u64* __restrict__ mask, const u32* __restrict__ svalid,
    u64* __restrict__ keepg) {
    __shared__ u64 keep[WORDS];
    __shared__ u32 ormL[WORDS], ormH[WORDS];
    const int tid = threadIdx.x;
    if (tid < WORDS) {
        u64 w0 = 0;
        for (int b = 0; b < 64; b++) {
            int idx = tid * 64 + b;
            if (idx < NCAND && svalid[idx]) w0 |= (1ull << b);
        }
        keep[tid] = w0; ormL[tid] = 0; ormH[tid] = 0;
    }
    __syncthreads();
    for (int t = 0; t < WORDS; t++) {
        if (tid < 64) {
            int row = t * 64 + tid;
            u64 d = (row < NCAND) ? mask[(size_t)row * WORDS + t] : 0ull;
            u32 dlo = (u32)d, dhi = (u32)(d >> 32);
            u64 cur = keep[t];
            u64 pending = cur;
            while (pending) {
                int b = __builtin_ctzll(pending);
                pending &= pending - 1;
                u64 mb = ((u64)__shfl(dhi, b, 64) << 32) | (u64)__shfl(dlo, b, 64);
                cur &= ~mb;
                pending &= ~mb;
            }
            if (tid == 0) keep[t] = cur;
        }
        __syncthreads();
        u64 kw = keep[t];
        int nW = WORDS - 1 - t;
        for (int task = tid; task < 64 * nW; task += 1024) {
            int r = task / nW, w = t + 1 + (task - r * nW);
            if ((kw >> r) & 1ull) {
                u64 mrow = mask[(size_t)(t * 64 + r) * WORDS + w];
                if (mrow) {
                    atomicOr(&ormL[w], (u32)mrow);
                    atomicOr(&ormH[w], (u32)(mrow >> 32));
                }
            }
        }
        __syncthreads();
        if (tid > t && tid < WORDS) {
            keep[tid] &= ~(((u64)ormH[tid] << 32) | (u64)ormL[tid]);
            ormL[tid] = 0; ormH[tid] = 0;
        }
        __syncthreads();
    }
    if (tid < WORDS) keepg[tid] = keep[tid];
}

// ---------------- kernel 7: final gather ----------------
__global__ __launch_bounds__(1024) void k_out(
    const u64* __restrict__ keepg, const float* __restrict__ sboxes,
    float* __restrict__ out) {
    __shared__ u32 sc[1024];
    __shared__ u64 kw[WORDS];
    const int tid = threadIdx.x;
    if (tid < WORDS) kw[tid] = keepg[tid];
    __syncthreads();
    const int i0 = tid * 5;
    u32 cnt = 0;
    for (int e = 0; e < 5; e++) {
        int i = i0 + e;
        if (i < NCAND) cnt += (u32)((kw[i >> 6] >> (i & 63)) & 1ull);
    }
    sc[tid] = cnt;
    __syncthreads();
    for (int off = 1; off < 1024; off <<= 1) {
        u32 v = (tid >= off) ? sc[tid - off] : 0;
        __syncthreads();
        sc[tid] += v;
        __syncthreads();
    }
    u32 incl = sc[tid];
    u32 total = sc[1023];
    u32 kr = incl - cnt;
    for (int e = 0; e < 5; e++) {
        int i = i0 + e;
        if (i < NCAND) {
            bool kp = (kw[i >> 6] >> (i & 63)) & 1ull;
            if (kp) {
                if (kr < 1000u) {
                    out[kr * 4 + 0] = sboxes[i * 4 + 0];
                    out[kr * 4 + 1] = sboxes[i * 4 + 1];
                    out[kr * 4 + 2] = sboxes[i * 4 + 2];
                    out[kr * 4 + 3] = sboxes[i * 4 + 3];
                }
                kr++;
            } else {
                u32 slot = total + (u32)i - kr;
                if (slot < 1000u) {
                    out[slot * 4 + 0] = sboxes[i * 4 + 0];
                    out[slot * 4 + 1] = sboxes[i * 4 + 1];
                    out[slot * 4 + 2] = sboxes[i * 4 + 2];
                    out[slot * 4 + 3] = sboxes[i * 4 + 3];
                }
            }
        }
    }
}

// ---------------- host ----------------
extern "C" void kernel_launch(void* const* d_in, const int* in_sizes, int n_in,
                              void* d_out, int out_size, void* d_ws, size_t ws_size,
                              hipStream_t stream) {
    (void)in_sizes; (void)n_in; (void)out_size; (void)ws_size;
    FeatPtrs fp;
    for (int i = 0; i < 5; i++) fp.p[i] = (const float*)d_in[i];
    const float* conv_w = (const float*)d_in[5];
    const float* conv_b = (const float*)d_in[6];
    const float* cls_w  = (const float*)d_in[7];
    const float* cls_b  = (const float*)d_in[8];
    const float* bbox_w = (const float*)d_in[9];
    const float* bbox_b = (const float*)d_in[10];

    char* ws = (char*)d_ws;
    f16*   whi    = (f16*)(ws + OFF_WHI);
    f16*   wlo    = (f16*)(ws + OFF_WLO);
    float* headw  = (float*)(ws + OFF_HEADW);
    float* headb  = (float*)(ws + OFF_HEADB);
    float* scores = (float*)(ws + OFF_SCORES);
    float* deltas = (float*)(ws + OFF_DELTAS);
    u64*   key    = (u64*)(ws + OFF_KEY);
    float* sboxes = (float*)(ws + OFF_SBOX);
    float* sob    = (float*)(ws + OFF_SOB);
    u32*   svalid = (u32*)(ws + OFF_SVAL);
    u64*   maskp  = (u64*)(ws + OFF_MASK);
    u64*   keepg  = (u64*)(ws + OFF_KEEP);

    k_prep<<<2304, 256, 0, stream>>>(conv_w, cls_w, cls_b, bbox_w, bbox_b,
                                     whi, wlo, headw, headb);

    k_conv<<<863, 256, 0, stream>>>(fp, whi, wlo, conv_b, headw, headb, scores, deltas);

    k_topk<<<5, 1024, 0, stream>>>(scores, key);

    DecParams dp;
    {
        const double sz[5] = {32.0, 64.0, 128.0, 256.0, 512.0};
        const double rt[3] = {0.5, 1.0, 2.0};
        for (int l = 0; l < 5; l++)
            for (int a = 0; a < 3; a++) {
                double hr = sqrt(rt[a]);
                double wr = 1.0 / hr;
                double w = wr * sz[l], h = hr * sz[l];
                dp.b[l][a][0] = (float)nearbyint(-w / 2.0);
                dp.b[l][a][1] = (float)nearbyint(-h / 2.0);
                dp.b[l][a][2] = (float)nearbyint(w / 2.0);
                dp.b[l][a][3] = (float)nearbyint(h / 2.0);
            }
    }
    k_sort<<<1, 1024, 0, stream>>>(key, deltas, dp, sboxes, sob, svalid);
    k_mask<<<(NCAND * WORDS + 255) / 256, 256, 0, stream>>>(sob, maskp);
    k_scan<<<1, 1024, 0, stream>>>(maskp, svalid, keepg);
    k_out<<<1, 1024, 0, stream>>>(keepg, sboxes, (float*)d_out);
}

// Round 10
// 1063.386 us; speedup vs baseline: 1.8804x; 1.0968x over previous
//
#include <hip/hip_runtime.h>
#include <cmath>

typedef unsigned int u32;
typedef unsigned long long u64;
typedef _Float16 f16;
typedef _Float16 f16x8 __attribute__((ext_vector_type(8)));
typedef float f32x4 __attribute__((ext_vector_type(4)));

// address-space-qualified typedefs for global_load_lds
typedef __attribute__((address_space(1))) const unsigned int gu32;
typedef __attribute__((address_space(3))) unsigned int lu32;

#define NCAND 4507
#define WORDS 71              // ceil(4507/64)
#define ROWS_AL (WORDS * 64)  // 4544
#define TOTS 159882           // total scores across levels

__constant__ int c_W[5]      = {200, 100, 50, 25, 13};
__constant__ int c_stride[5] = {4, 8, 16, 32, 61};
__constant__ int c_Nl[5]     = {120000, 30000, 7500, 1875, 507};
__constant__ int c_soff[5]   = {0, 120000, 150000, 157500, 159375};
__constant__ int c_k[5]      = {1000, 1000, 1000, 1000, 507};

// unified conv grid: tiles per level (8x8 px tiles): 625,169,49,16,4
__constant__ int cv_boff[6]  = {0, 625, 794, 843, 859, 863};

struct DecParams { float b[5][3][4]; };
struct FeatPtrs { const float* p[5]; };

__device__ __forceinline__ u32 flipf(float f) {
    u32 u = __float_as_uint(f);
    return (u & 0x80000000u) ? ~u : (u | 0x80000000u);
}

// ---------------- workspace layout ----------------
constexpr size_t AL(size_t x) { return (x + 255) & ~(size_t)255; }
constexpr size_t OFF_WHI    = 0;                                   // 589824 f16 = 1179648 B
constexpr size_t OFF_WLO    = AL(OFF_WHI + 1179648);               // 589824 f16
constexpr size_t OFF_HEADW  = AL(OFF_WLO + 1179648);               // 15*256 f
constexpr size_t OFF_HEADB  = AL(OFF_HEADW + 3840 * 4);            // 15 f
constexpr size_t OFF_SCORES = AL(OFF_HEADB + 64);                  // TOTS f
constexpr size_t OFF_DELTAS = AL(OFF_SCORES + (size_t)TOTS * 4);   // TOTS*4 f
constexpr size_t OFF_KEY    = AL(OFF_DELTAS + (size_t)TOTS * 16);  // NCAND u64
constexpr size_t OFF_SBOX   = AL(OFF_KEY + (size_t)NCAND * 8);     // NCAND*4 f
constexpr size_t OFF_SOB    = AL(OFF_SBOX + (size_t)NCAND * 16);   // NCAND*4 f
constexpr size_t OFF_SVAL   = AL(OFF_SOB + (size_t)NCAND * 16);    // NCAND u32
constexpr size_t OFF_MASK   = AL(OFF_SVAL + (size_t)NCAND * 4);    // ROWS_AL*WORDS u64
constexpr size_t OFF_KEEP   = AL(OFF_MASK + (size_t)ROWS_AL * WORDS * 8); // WORDS u64

// ---------------- kernel 1: weight prep (OUTPUT-LINEAR, coalesced writes) ----------------
// Thread i owns output f16 ELEMENT i (0..589823 — r9 BUG: used the byte count
// 1179648 as the bound -> wrote 2x past whi/wlo, clobbering wlo+headw).
// Inverts the bijective layout permutation:
//   block = (chunk*9 + ky*3+kx) of 8192 f16; within = co*32 + slot*8 + j,
//   slot = (cir>>3) ^ ((co>>1)&3)  =>  cir = ((slot ^ ((co>>1)&3))<<3) | j.
__global__ __launch_bounds__(256) void k_prep(
    const float* __restrict__ cw, const float* __restrict__ clsw,
    const float* __restrict__ clsb, const float* __restrict__ bw,
    const float* __restrict__ bb, f16* __restrict__ whi, f16* __restrict__ wlo,
    float* __restrict__ headw, float* __restrict__ headb) {
    int i = blockIdx.x * 256 + threadIdx.x;
    if (i < 589824) {
        int blk = i >> 13;          // 72 blocks of 8192 f16
        int within = i & 8191;
        int co = within >> 5;
        int rem = within & 31;
        int slot = rem >> 3, j = rem & 7;
        int chunk = blk / 9, kk = blk - chunk * 9;
        int ky = kk / 3, kx = kk - ky * 3;
        int g = slot ^ ((co >> 1) & 3);
        int ci = (chunk << 5) | (g << 3) | j;
        float w = cw[(((co << 8) + ci) * 3 + ky) * 3 + kx];
        f16 hi = (f16)w;
        whi[i] = hi;
        wlo[i] = (f16)((w - (float)hi) * 2048.0f);
    }
    if (i < 3840) {
        int h = i >> 8, ci = i & 255;
        headw[i] = (h < 3) ? clsw[h * 256 + ci] : bw[(h - 3) * 256 + ci];
    }
    if (i < 15) headb[i] = (i < 3) ? clsb[i] : bb[i - 3];
}

// ---------------- kernel 2: MFMA fp16-split conv3x3+ReLU + 1x1 heads ----------------
// 512 threads = 8 waves; per block M=64 px (8x8 tile), N=256 co; wave = 64px x 32co
// (halves per-wave acc vs r8: 64 acc VGPRs -> target <=128 total for 4 waves/SIMD).
// A patch in LDS with XOR bank swizzle baked into write+read (r8 had 4-way conflicts,
// 7.95M SQ_LDS_BANK_CONFLICT): f16 idx = py*320 + px*32 + ((ci>>3)^((px>>1)&3))*8 + (ci&7).
// B: pre-swizzled global blocks, double-buffered via global_load_lds (linear dest).
// Inner 9-tap loop fully unrolled -> ky/kx compile-time (no runtime-indexed arrays).
// D = acc1 + acc2 * 2^-11 (3-pass fp16 split, lo pre-scaled 2^11; verified r8 absmax 0.0).
__global__ __launch_bounds__(512) void k_conv(
    FeatPtrs fp, const f16* __restrict__ whi, const f16* __restrict__ wlo,
    const float* __restrict__ convb, const float* __restrict__ headw,
    const float* __restrict__ headb, float* __restrict__ scores,
    float* __restrict__ deltas) {
    __shared__ float4 smq[4896];  // 78336 B: A hi/lo 2x6400 @0, B 2x32768 @12800
    char* smb = (char*)smq;
    const int tid = threadIdx.x;
    const int lane = tid & 63, wv = tid >> 6;
    const int l15 = lane & 15, l4 = lane >> 4;

    // level lookup
    const int bid = blockIdx.x;
    int l = 0;
#pragma unroll
    for (int q = 1; q < 5; q++) if (bid >= cv_boff[q]) l = q;
    const int H = c_W[l], W = H;
    const int soff = c_soff[l];
    const float* __restrict__ in = fp.p[l];
    const int t = bid - cv_boff[l];
    const int tilesx = (W + 7) >> 3;
    const int tx = t % tilesx, ty = t / tilesx;
    const int x0 = tx * 8, y0 = ty * 8;
    const int HW = H * W;

    // A-read addressing: byte = (r+ky)*640 + colx(kx), colx = p*64 + ((l4^((p>>1)&3))<<4),
    // p = (lane&7)+kx. Banks: 16*p + 4*(l4^((p>>1)&3)) mod 32 -> 32 distinct over (p,l4),
    // row stride 640B is bank-neutral -> 2-way (free).
    int rbase0, rbase1, rbase2, rbase3;
    {
        int rr = l15 >> 3;
        rbase0 = (0 + rr) * 640; rbase1 = (2 + rr) * 640;
        rbase2 = (4 + rr) * 640; rbase3 = (6 + rr) * 640;
    }
    int colx0, colx1, colx2;
    {
        int c = lane & 7;
        int p0 = c, p1 = c + 1, p2 = c + 2;
        colx0 = p0 * 64 + ((l4 ^ ((p0 >> 1) & 3)) << 4);
        colx1 = p1 * 64 + ((l4 ^ ((p1 >> 1) & 3)) << 4);
        colx2 = p2 * 64 + ((l4 ^ ((p2 >> 1) & 3)) << 4);
    }
    // B-fragment offsets (2 N-tiles of this wave) within a 16KB block
    int bco0 = wv * 32 + l15, bco1 = wv * 32 + 16 + l15;
    const int boff0 = bco0 * 64 + ((l4 ^ ((bco0 >> 1) & 3)) << 4);
    const int boff1 = bco1 * 64 + ((l4 ^ ((bco1 >> 1) & 3)) << 4);

    f32x4 acc1[4][2], acc2[4][2];
#pragma unroll
    for (int mt = 0; mt < 4; mt++)
#pragma unroll
        for (int nt = 0; nt < 2; nt++) {
            acc1[mt][nt] = (f32x4)0.0f;
            acc2[mt][nt] = (f32x4)0.0f;
        }

    // stage channel-last fp16 patch (hi @0, scaled-lo @6400), XOR-swizzled write
    auto stagePatch = [&](int chunk) {
        const int c0 = chunk << 5;
        f16* ph = (f16*)smb;
        f16* pl = (f16*)(smb + 6400);
        for (int e = tid; e < 3200; e += 512) {
            int py = e / 320, rem = e - py * 320;
            int px = rem >> 5, ci = rem & 31;
            int gy = y0 - 1 + py, gx = x0 - 1 + px;
            float v = 0.f;
            if (gy >= 0 && gy < H && gx >= 0 && gx < W)
                v = in[(c0 + ci) * HW + gy * W + gx];
            f16 hi = (f16)v;
            int widx = py * 320 + px * 32 + (((ci >> 3) ^ ((px >> 1) & 3)) << 3) + (ci & 7);
            ph[widx] = hi;
            pl[widx] = (f16)((v - (float)hi) * 2048.0f);
        }
    };
    // async-stage B block sidx into buffer buf (hi 16KB + lo 16KB), linear dest
    auto issueB = [&](int sidx, int buf) {
        const char* gh = (const char*)whi + (size_t)sidx * 16384;
        const char* gl = (const char*)wlo + (size_t)sidx * 16384;
        char* dh = smb + 12800 + buf * 32768;
        char* dl = dh + 16384;
#pragma unroll
        for (int q = 0; q < 2; q++) {
            int i1 = (wv * 2 + q) * 1024;
            __builtin_amdgcn_global_load_lds((gu32*)(gh + i1 + lane * 16), (lu32*)(dh + i1), 16, 0, 0);
            __builtin_amdgcn_global_load_lds((gu32*)(gl + i1 + lane * 16), (lu32*)(dl + i1), 16, 0, 0);
        }
    };

    stagePatch(0);
    issueB(0, 0);
    __syncthreads();

    for (int chunk = 0; chunk < 8; ++chunk) {
        if (chunk) { stagePatch(chunk); __syncthreads(); }
#pragma unroll
        for (int kk = 0; kk < 9; ++kk) {
            const int s = chunk * 9 + kk;
            const int buf = s & 1;
            if (s < 71) issueB(s + 1, buf ^ 1);
            {
                const int ky = kk / 3, kx = kk - ky * 3;
                const int kyb = ky * 640;
                const int cx = (kx == 0) ? colx0 : (kx == 1) ? colx1 : colx2;
                const char* bh = smb + 12800 + buf * 32768;
                const char* bl = bh + 16384;
                f16x8 ah0 = *(const f16x8*)(smb + rbase0 + kyb + cx);
                f16x8 ah1 = *(const f16x8*)(smb + rbase1 + kyb + cx);
                f16x8 ah2 = *(const f16x8*)(smb + rbase2 + kyb + cx);
                f16x8 ah3 = *(const f16x8*)(smb + rbase3 + kyb + cx);
                f16x8 al0 = *(const f16x8*)(smb + 6400 + rbase0 + kyb + cx);
                f16x8 al1 = *(const f16x8*)(smb + 6400 + rbase1 + kyb + cx);
                f16x8 al2 = *(const f16x8*)(smb + 6400 + rbase2 + kyb + cx);
                f16x8 al3 = *(const f16x8*)(smb + 6400 + rbase3 + kyb + cx);
#pragma unroll
                for (int nt = 0; nt < 2; nt++) {
                    const int bo = nt ? boff1 : boff0;
                    f16x8 vbh = *(const f16x8*)(bh + bo);
                    f16x8 vbl = *(const f16x8*)(bl + bo);
                    acc1[0][nt] = __builtin_amdgcn_mfma_f32_16x16x32_f16(ah0, vbh, acc1[0][nt], 0, 0, 0);
                    acc2[0][nt] = __builtin_amdgcn_mfma_f32_16x16x32_f16(ah0, vbl, acc2[0][nt], 0, 0, 0);
                    acc2[0][nt] = __builtin_amdgcn_mfma_f32_16x16x32_f16(al0, vbh, acc2[0][nt], 0, 0, 0);
                    acc1[1][nt] = __builtin_amdgcn_mfma_f32_16x16x32_f16(ah1, vbh, acc1[1][nt], 0, 0, 0);
                    acc2[1][nt] = __builtin_amdgcn_mfma_f32_16x16x32_f16(ah1, vbl, acc2[1][nt], 0, 0, 0);
                    acc2[1][nt] = __builtin_amdgcn_mfma_f32_16x16x32_f16(al1, vbh, acc2[1][nt], 0, 0, 0);
                    acc1[2][nt] = __builtin_amdgcn_mfma_f32_16x16x32_f16(ah2, vbh, acc1[2][nt], 0, 0, 0);
                    acc2[2][nt] = __builtin_amdgcn_mfma_f32_16x16x32_f16(ah2, vbl, acc2[2][nt], 0, 0, 0);
                    acc2[2][nt] = __builtin_amdgcn_mfma_f32_16x16x32_f16(al2, vbh, acc2[2][nt], 0, 0, 0);
                    acc1[3][nt] = __builtin_amdgcn_mfma_f32_16x16x32_f16(ah3, vbh, acc1[3][nt], 0, 0, 0);
                    acc2[3][nt] = __builtin_amdgcn_mfma_f32_16x16x32_f16(ah3, vbl, acc2[3][nt], 0, 0, 0);
                    acc2[3][nt] = __builtin_amdgcn_mfma_f32_16x16x32_f16(al3, vbh, acc2[3][nt], 0, 0, 0);
                }
            }
            __syncthreads();
        }
    }

    // epilogue: combine split, + bias, ReLU -> t in acc1
    const float INV2048 = 4.8828125e-4f;
    {
        float cb0 = convb[bco0], cb1 = convb[bco1];
#pragma unroll
        for (int mt = 0; mt < 4; mt++)
#pragma unroll
            for (int nt = 0; nt < 2; nt++) {
                float cb = nt ? cb1 : cb0;
#pragma unroll
                for (int r = 0; r < 4; r++) {
                    float tv = acc1[mt][nt][r] + acc2[mt][nt][r] * INV2048 + cb;
                    acc1[mt][nt][r] = tv > 0.f ? tv : 0.f;
                }
            }
    }

    // heads: per-thread partial over its 2 co, butterfly over 16 col-lanes (=32 co),
    // cross-wave sum (8 parts) via LDS in fixed order.
    float* part = (float*)smb;  // [8 wv][64 px][3]
    for (int hc = 0; hc < 15; hc += 3) {
        float hw3[3][2];
#pragma unroll
        for (int h3 = 0; h3 < 3; h3++) {
            hw3[h3][0] = headw[(hc + h3) * 256 + bco0];
            hw3[h3][1] = headw[(hc + h3) * 256 + bco1];
        }
#pragma unroll
        for (int mt = 0; mt < 4; mt++)
#pragma unroll
            for (int r = 0; r < 4; r++) {
                float p0 = 0.f, p1 = 0.f, p2 = 0.f;
#pragma unroll
                for (int nt = 0; nt < 2; nt++) {
                    float tv = acc1[mt][nt][r];
                    p0 = fmaf(hw3[0][nt], tv, p0);
                    p1 = fmaf(hw3[1][nt], tv, p1);
                    p2 = fmaf(hw3[2][nt], tv, p2);
                }
                p0 += __shfl_xor(p0, 1); p0 += __shfl_xor(p0, 2); p0 += __shfl_xor(p0, 4); p0 += __shfl_xor(p0, 8);
                p1 += __shfl_xor(p1, 1); p1 += __shfl_xor(p1, 2); p1 += __shfl_xor(p1, 4); p1 += __shfl_xor(p1, 8);
                p2 += __shfl_xor(p2, 1); p2 += __shfl_xor(p2, 2); p2 += __shfl_xor(p2, 4); p2 += __shfl_xor(p2, 8);
                if (l15 == 0) {
                    int px = mt * 16 + l4 * 4 + r;
                    part[(wv * 64 + px) * 3 + 0] = p0;
                    part[(wv * 64 + px) * 3 + 1] = p1;
                    part[(wv * 64 + px) * 3 + 2] = p2;
                }
            }
        __syncthreads();
        if (tid < 192) {
            int px = tid / 3, h3 = tid % 3;
            int h = hc + h3;
            float sum = 0.f;
#pragma unroll
            for (int g = 0; g < 8; g++) sum += part[(g * 64 + px) * 3 + h3];
            sum += headb[h];
            int gy = y0 + (px >> 3), gx = x0 + (px & 7);
            if (gy < H && gx < W) {
                int pix = gy * W + gx;
                if (h < 3) {
                    scores[soff + pix * 3 + h] = sum;
                } else {
                    int ch2 = h - 3;
                    deltas[((size_t)(soff + pix * 3 + (ch2 >> 2))) * 4 + (ch2 & 3)] = sum;
                }
            }
        }
        __syncthreads();
    }
}

// ---------------- kernel 3: per-level exact top-k (radix select) ----------------
__global__ __launch_bounds__(1024) void k_topk(
    const float* __restrict__ scores, u64* __restrict__ key) {
    const int l = blockIdx.x;
    const int Nl = c_Nl[l], off = c_soff[l], k = c_k[l];
    const int base = l * 1000;
    const int tid = threadIdx.x;
    const u32 lshift = (u32)l << 24;
    __shared__ u32 histw[16][256];
    __shared__ u32 hist[256];
    __shared__ u32 sh_prefix, sh_m, sh_sel, sh_tie;
    __shared__ u32 tiebuf[2048];
    if (tid == 0) { sh_sel = 0; sh_tie = 0; }
    __syncthreads();

    if (k == Nl) {
        for (int i = tid; i < Nl; i += 1024) {
            u32 p = atomicAdd(&sh_sel, 1u);
            u32 k32 = flipf(scores[off + i]);
            key[base + p] = ((u64)(~k32) << 32) | (u64)(lshift | (u32)i);
        }
        return;
    }
    const int wid = tid >> 6;
    u32 prefix = 0, m = (u32)k;
    for (int p = 0; p < 4; p++) {
        int shift = 24 - 8 * p;
        for (int b = tid; b < 4096; b += 1024) ((u32*)histw)[b] = 0;
        __syncthreads();
        for (int i = tid; i < Nl; i += 1024) {
            u32 k32 = flipf(scores[off + i]);
            if (p == 0 || (k32 >> (shift + 8)) == prefix)
                atomicAdd(&histw[wid][(k32 >> shift) & 255u], 1u);
        }
        __syncthreads();
        for (int b = tid; b < 256; b += 1024) {
            u32 s = 0;
#pragma unroll
            for (int w = 0; w < 16; w++) s += histw[w][b];
            hist[b] = s;
        }
        __syncthreads();
        if (tid == 0) {
            u32 cum = 0;
            for (int b = 255; b >= 0; --b) {
                u32 c = hist[b];
                if (cum + c >= m) { sh_prefix = (prefix << 8) | (u32)b; sh_m = m - cum; break; }
                cum += c;
            }
        }
        __syncthreads();
        prefix = sh_prefix; m = sh_m;
        __syncthreads();
    }
    for (int i = tid; i < Nl; i += 1024) {
        u32 k32 = flipf(scores[off + i]);
        if (k32 > prefix) {
            u32 p = atomicAdd(&sh_sel, 1u);
            key[base + p] = ((u64)(~k32) << 32) | (u64)(lshift | (u32)i);
        } else if (k32 == prefix) {
            u32 t = atomicAdd(&sh_tie, 1u);
            if (t < 2048u) tiebuf[t] = (u32)i;
        }
    }
    __syncthreads();
    u32 nsel = sh_sel;
    u32 ntie = sh_tie; if (ntie > 2048u) ntie = 2048u;
    if (ntie != m) {
        for (u32 j = tid; j < 2048; j += 1024) if (j >= ntie) tiebuf[j] = 0xFFFFFFFFu;
        __syncthreads();
        for (u32 ksz = 2; ksz <= 2048; ksz <<= 1) {
            for (u32 jj = ksz >> 1; jj > 0; jj >>= 1) {
                for (u32 i2 = tid; i2 < 2048; i2 += 1024) {
                    u32 ixj = i2 ^ jj;
                    if (ixj > i2) {
                        u32 a = tiebuf[i2], b = tiebuf[ixj];
                        bool up = ((i2 & ksz) == 0);
                        if ((a > b) == up) { tiebuf[i2] = b; tiebuf[ixj] = a; }
                    }
                }
                __syncthreads();
            }
        }
    }
    for (u32 j = tid; j < m; j += 1024)
        key[base + nsel + j] = ((u64)(~prefix) << 32) | (u64)(lshift | tiebuf[j]);
}

// ---------------- kernel 4: global bitonic sort + inline decode ----------------
__global__ __launch_bounds__(1024) void k_sort(
    const u64* __restrict__ key, const float* __restrict__ deltas, DecParams P,
    float* __restrict__ sboxes, float* __restrict__ sob, u32* __restrict__ svalid) {
    __shared__ u64 sk[8192];
    const int tid = threadIdx.x;
    for (int i = tid; i < 8192; i += 1024) sk[i] = (i < NCAND) ? key[i] : ~0ull;
    __syncthreads();
    for (u32 ksz = 2; ksz <= 8192; ksz <<= 1) {
        for (u32 j = ksz >> 1; j > 0; j >>= 1) {
            for (u32 i = tid; i < 8192; i += 1024) {
                u32 ixj = i ^ j;
                if (ixj > i) {
                    u64 a = sk[i], b = sk[ixj];
                    bool up = ((i & ksz) == 0);
                    if ((a > b) == up) { sk[i] = b; sk[ixj] = a; }
                }
            }
            __syncthreads();
        }
    }
    const float CLAMP = 4.135166556742356f;
    for (int s = tid; s < NCAND; s += 1024) {
        u32 info = (u32)sk[s];
        int l = info >> 24, idx = info & 0xFFFFFF;
        int W = c_W[l], st = c_stride[l];
        int a = idx % 3, pix = idx / 3;
        int x = pix % W, y = pix / W;
        float ax1 = x * st + P.b[l][a][0];
        float ay1 = y * st + P.b[l][a][1];
        float ax2 = x * st + P.b[l][a][2];
        float ay2 = y * st + P.b[l][a][3];
        float w_ = ax2 - ax1, h_ = ay2 - ay1;
        float cx = ax1 + 0.5f * w_, cy = ay1 + 0.5f * h_;
        const float* d = deltas + ((size_t)(c_soff[l] + idx)) * 4;
        float dx = d[0], dy = d[1];
        float dw = fminf(d[2], CLAMP), dh = fminf(d[3], CLAMP);
        float pcx = dx * w_ + cx, pcy = dy * h_ + cy;
        float pw = expf(dw) * w_, ph = expf(dh) * h_;
        float x1 = pcx - 0.5f * pw, y1 = pcy - 0.5f * ph;
        float x2 = pcx + 0.5f * pw, y2 = pcy + 0.5f * ph;
        x1 = fminf(fmaxf(x1, 0.f), 800.f); y1 = fminf(fmaxf(y1, 0.f), 800.f);
        x2 = fminf(fmaxf(x2, 0.f), 800.f); y2 = fminf(fmaxf(y2, 0.f), 800.f);
        u32 vv = (x2 - x1 >= 0.001f && y2 - y1 >= 0.001f) ? 1u : 0u;
        float offv = (float)l * 801.0f;
        sboxes[s * 4 + 0] = x1; sboxes[s * 4 + 1] = y1;
        sboxes[s * 4 + 2] = x2; sboxes[s * 4 + 3] = y2;
        sob[s * 4 + 0] = x1 + offv; sob[s * 4 + 1] = y1 + offv;
        sob[s * 4 + 2] = x2 + offv; sob[s * 4 + 3] = y2 + offv;
        svalid[s] = vv;
    }
}

// ---------------- kernel 5: IoU suppression bitmask ----------------
__global__ __launch_bounds__(256) void k_mask(
    const float* __restrict__ sob, u64* __restrict__ mask) {
    int gid = blockIdx.x * 256 + threadIdx.x;
    const int total = NCAND * WORDS;
    if (gid >= total) return;
    int i = gid / WORDS, w = gid - i * WORDS;
    float bx1 = sob[i * 4], by1 = sob[i * 4 + 1], bx2 = sob[i * 4 + 2], by2 = sob[i * 4 + 3];
    float ai = (bx2 - bx1) * (by2 - by1);
    u64 bits = 0;
    int j0 = w * 64;
    for (int b = 0; b < 64; b++) {
        int j = j0 + b;
        if (j < NCAND && j > i) {
            float cx1 = sob[j * 4], cy1 = sob[j * 4 + 1], cx2 = sob[j * 4 + 2], cy2 = sob[j * 4 + 3];
            float lt0 = fmaxf(bx1, cx1), lt1 = fmaxf(by1, cy1);
            float rb0 = fminf(bx2, cx2), rb1 = fminf(by2, cy2);
            float ww = fmaxf(rb0 - lt0, 0.f), hh = fmaxf(rb1 - lt1, 0.f);
            float inter = ww * hh;
            float aj = (cx2 - cx1) * (cy2 - cy1);
            float u = ai + aj - inter;
            float iou = inter / u;
            if (iou > 0.7f) bits |= (1ull << b);
        }
    }
    mask[(size_t)i * WORDS + w] = bits;
}

// ---------------- kernel 6: tiled greedy NMS scan (single block, 1024 thr) ----------------
__global__ __launch_bounds__(1024) void k_scan(
    const u64* __restrict__ mask, const u32* __restrict__ svalid,
    u64* __restrict__ keepg) {
    __shared__ u64 keep[WORDS];
    __shared__ u32 ormL[WORDS], ormH[WORDS];
    const int tid = threadIdx.x;
    if (tid < WORDS) {
        u64 w0 = 0;
        for (int b = 0; b < 64; b++) {
            int idx = tid * 64 + b;
            if (idx < NCAND && svalid[idx]) w0 |= (1ull << b);
        }
        keep[tid] = w0; ormL[tid] = 0; ormH[tid] = 0;
    }
    __syncthreads();
    for (int t = 0; t < WORDS; t++) {
        if (tid < 64) {
            int row = t * 64 + tid;
            u64 d = (row < NCAND) ? mask[(size_t)row * WORDS + t] : 0ull;
            u32 dlo = (u32)d, dhi = (u32)(d >> 32);
            u64 cur = keep[t];
            u64 pending = cur;
            while (pending) {
                int b = __builtin_ctzll(pending);
                pending &= pending - 1;
                u64 mb = ((u64)__shfl(dhi, b, 64) << 32) | (u64)__shfl(dlo, b, 64);
                cur &= ~mb;
                pending &= ~mb;
            }
            if (tid == 0) keep[t] = cur;
        }
        __syncthreads();
        u64 kw = keep[t];
        int nW = WORDS - 1 - t;
        for (int task = tid; task < 64 * nW; task += 1024) {
            int r = task / nW, w = t + 1 + (task - r * nW);
            if ((kw >> r) & 1ull) {
                u64 mrow = mask[(size_t)(t * 64 + r) * WORDS + w];
                if (mrow) {
                    atomicOr(&ormL[w], (u32)mrow);
                    atomicOr(&ormH[w], (u32)(mrow >> 32));
                }
            }
        }
        __syncthreads();
        if (tid > t && tid < WORDS) {
            keep[tid] &= ~(((u64)ormH[tid] << 32) | (u64)ormL[tid]);
            ormL[tid] = 0; ormH[tid] = 0;
        }
        __syncthreads();
    }
    if (tid < WORDS) keepg[tid] = keep[tid];
}

// ---------------- kernel 7: final gather ----------------
__global__ __launch_bounds__(1024) void k_out(
    const u64* __restrict__ keepg, const float* __restrict__ sboxes,
    float* __restrict__ out) {
    __shared__ u32 sc[1024];
    __shared__ u64 kw[WORDS];
    const int tid = threadIdx.x;
    if (tid < WORDS) kw[tid] = keepg[tid];
    __syncthreads();
    const int i0 = tid * 5;
    u32 cnt = 0;
    for (int e = 0; e < 5; e++) {
        int i = i0 + e;
        if (i < NCAND) cnt += (u32)((kw[i >> 6] >> (i & 63)) & 1ull);
    }
    sc[tid] = cnt;
    __syncthreads();
    for (int off = 1; off < 1024; off <<= 1) {
        u32 v = (tid >= off) ? sc[tid - off] : 0;
        __syncthreads();
        sc[tid] += v;
        __syncthreads();
    }
    u32 incl = sc[tid];
    u32 total = sc[1023];
    u32 kr = incl - cnt;
    for (int e = 0; e < 5; e++) {
        int i = i0 + e;
        if (i < NCAND) {
            bool kp = (kw[i >> 6] >> (i & 63)) & 1ull;
            if (kp) {
                if (kr < 1000u) {
                    out[kr * 4 + 0] = sboxes[i * 4 + 0];
                    out[kr * 4 + 1] = sboxes[i * 4 + 1];
                    out[kr * 4 + 2] = sboxes[i * 4 + 2];
                    out[kr * 4 + 3] = sboxes[i * 4 + 3];
                }
                kr++;
            } else {
                u32 slot = total + (u32)i - kr;
                if (slot < 1000u) {
                    out[slot * 4 + 0] = sboxes[i * 4 + 0];
                    out[slot * 4 + 1] = sboxes[i * 4 + 1];
                    out[slot * 4 + 2] = sboxes[i * 4 + 2];
                    out[slot * 4 + 3] = sboxes[i * 4 + 3];
                }
            }
        }
    }
}

// ---------------- host ----------------
extern "C" void kernel_launch(void* const* d_in, const int* in_sizes, int n_in,
                              void* d_out, int out_size, void* d_ws, size_t ws_size,
                              hipStream_t stream) {
    (void)in_sizes; (void)n_in; (void)out_size; (void)ws_size;
    FeatPtrs fp;
    for (int i = 0; i < 5; i++) fp.p[i] = (const float*)d_in[i];
    const float* conv_w = (const float*)d_in[5];
    const float* conv_b = (const float*)d_in[6];
    const float* cls_w  = (const float*)d_in[7];
    const float* cls_b  = (const float*)d_in[8];
    const float* bbox_w = (const float*)d_in[9];
    const float* bbox_b = (const float*)d_in[10];

    char* ws = (char*)d_ws;
    f16*   whi    = (f16*)(ws + OFF_WHI);
    f16*   wlo    = (f16*)(ws + OFF_WLO);
    float* headw  = (float*)(ws + OFF_HEADW);
    float* headb  = (float*)(ws + OFF_HEADB);
    float* scores = (float*)(ws + OFF_SCORES);
    float* deltas = (float*)(ws + OFF_DELTAS);
    u64*   key    = (u64*)(ws + OFF_KEY);
    float* sboxes = (float*)(ws + OFF_SBOX);
    float* sob    = (float*)(ws + OFF_SOB);
    u32*   svalid = (u32*)(ws + OFF_SVAL);
    u64*   maskp  = (u64*)(ws + OFF_MASK);
    u64*   keepg  = (u64*)(ws + OFF_KEEP);

    k_prep<<<2304, 256, 0, stream>>>(conv_w, cls_w, cls_b, bbox_w, bbox_b,
                                     whi, wlo, headw, headb);

    k_conv<<<863, 512, 0, stream>>>(fp, whi, wlo, conv_b, headw, headb, scores, deltas);

    k_topk<<<5, 1024, 0, stream>>>(scores, key);

    DecParams dp;
    {
        const double sz[5] = {32.0, 64.0, 128.0, 256.0, 512.0};
        const double rt[3] = {0.5, 1.0, 2.0};
        for (int l = 0; l < 5; l++)
            for (int a = 0; a < 3; a++) {
                double hr = sqrt(rt[a]);
                double wr = 1.0 / hr;
                double w = wr * sz[l], h = hr * sz[l];
                dp.b[l][a][0] = (float)nearbyint(-w / 2.0);
                dp.b[l][a][1] = (float)nearbyint(-h / 2.0);
                dp.b[l][a][2] = (float)nearbyint(w / 2.0);
                dp.b[l][a][3] = (float)nearbyint(h / 2.0);
            }
    }
    k_sort<<<1, 1024, 0, stream>>>(key, deltas, dp, sboxes, sob, svalid);
    k_mask<<<(NCAND * WORDS + 255) / 256, 256, 0, stream>>>(sob, maskp);
    k_scan<<<1, 1024, 0, stream>>>(maskp, svalid, keepg);
    k_out<<<1, 1024, 0, stream>>>(keepg, sboxes, (float*)d_out);
}

// Round 11
// 980.873 us; speedup vs baseline: 2.0385x; 1.0841x over previous
//
#include <hip/hip_runtime.h>
#include <cmath>

typedef unsigned int u32;
typedef unsigned long long u64;
typedef _Float16 f16;
typedef _Float16 f16x8 __attribute__((ext_vector_type(8)));
typedef float f32x4 __attribute__((ext_vector_type(4)));

// address-space-qualified typedefs for global_load_lds
typedef __attribute__((address_space(1))) const unsigned int gu32;
typedef __attribute__((address_space(3))) unsigned int lu32;

#define NCAND 4507
#define WORDS 71              // ceil(4507/64)
#define ROWS_AL (WORDS * 64)  // 4544
#define TOTS 159882           // total scores across levels

__constant__ int c_W[5]      = {200, 100, 50, 25, 13};
__constant__ int c_stride[5] = {4, 8, 16, 32, 61};
__constant__ int c_Nl[5]     = {120000, 30000, 7500, 1875, 507};
__constant__ int c_soff[5]   = {0, 120000, 150000, 157500, 159375};
__constant__ int c_k[5]      = {1000, 1000, 1000, 1000, 507};

// unified conv grid: tiles per level (8x8 px tiles): 625,169,49,16,4
__constant__ int cv_boff[6]  = {0, 625, 794, 843, 859, 863};

struct DecParams { float b[5][3][4]; };
struct FeatPtrs { const float* p[5]; };

__device__ __forceinline__ u32 flipf(float f) {
    u32 u = __float_as_uint(f);
    return (u & 0x80000000u) ? ~u : (u | 0x80000000u);
}

// ---------------- workspace layout ----------------
constexpr size_t AL(size_t x) { return (x + 255) & ~(size_t)255; }
constexpr size_t OFF_WHI    = 0;                                   // 589824 f16 = 1179648 B
constexpr size_t OFF_WLO    = AL(OFF_WHI + 1179648);               // 589824 f16
constexpr size_t OFF_HEADW  = AL(OFF_WLO + 1179648);               // 15*256 f
constexpr size_t OFF_HEADB  = AL(OFF_HEADW + 3840 * 4);            // 15 f
constexpr size_t OFF_SCORES = AL(OFF_HEADB + 64);                  // TOTS f
constexpr size_t OFF_DELTAS = AL(OFF_SCORES + (size_t)TOTS * 4);   // TOTS*4 f
constexpr size_t OFF_KEY    = AL(OFF_DELTAS + (size_t)TOTS * 16);  // NCAND u64
constexpr size_t OFF_SBOX   = AL(OFF_KEY + (size_t)NCAND * 8);     // NCAND*4 f
constexpr size_t OFF_SOB    = AL(OFF_SBOX + (size_t)NCAND * 16);   // NCAND*4 f
constexpr size_t OFF_SVAL   = AL(OFF_SOB + (size_t)NCAND * 16);    // NCAND u32
constexpr size_t OFF_MASK   = AL(OFF_SVAL + (size_t)NCAND * 4);    // ROWS_AL*WORDS u64 (2.58 MB)
constexpr size_t OFF_KEEP   = AL(OFF_MASK + (size_t)ROWS_AL * WORDS * 8); // WORDS u64
constexpr size_t OFF_GHIST  = AL(OFF_KEEP + WORDS * 8);            // 5*256 u32
// NOTE: k_topk2 uses the MASK region as scratch (2x TOTS u64 = 2.56 MB <= 2.58 MB);
// safe because k_mask fully rewrites MASK afterwards and k_scan only reads rows < NCAND.

// ---------------- kernel 1: weight prep (OUTPUT-LINEAR, coalesced writes) ----------------
// Thread i owns output f16 ELEMENT i (0..589823). Inverts the bijective layout perm:
//   block = (chunk*9 + ky*3+kx) of 8192 f16; within = co*32 + slot*8 + j,
//   slot = (cir>>3) ^ ((co>>1)&3)  =>  cir = ((slot ^ ((co>>1)&3))<<3) | j.
// Also zeroes ghist (k_hist accumulates into it each launch).
__global__ __launch_bounds__(256) void k_prep(
    const float* __restrict__ cw, const float* __restrict__ clsw,
    const float* __restrict__ clsb, const float* __restrict__ bw,
    const float* __restrict__ bb, f16* __restrict__ whi, f16* __restrict__ wlo,
    float* __restrict__ headw, float* __restrict__ headb, u32* __restrict__ ghist) {
    int i = blockIdx.x * 256 + threadIdx.x;
    if (i < 589824) {
        int blk = i >> 13;          // 72 blocks of 8192 f16
        int within = i & 8191;
        int co = within >> 5;
        int rem = within & 31;
        int slot = rem >> 3, j = rem & 7;
        int chunk = blk / 9, kk = blk - chunk * 9;
        int ky = kk / 3, kx = kk - ky * 3;
        int g = slot ^ ((co >> 1) & 3);
        int ci = (chunk << 5) | (g << 3) | j;
        float w = cw[(((co << 8) + ci) * 3 + ky) * 3 + kx];
        f16 hi = (f16)w;
        whi[i] = hi;
        wlo[i] = (f16)((w - (float)hi) * 2048.0f);
    }
    if (i < 3840) {
        int h = i >> 8, ci = i & 255;
        headw[i] = (h < 3) ? clsw[h * 256 + ci] : bw[(h - 3) * 256 + ci];
    }
    if (i < 15) headb[i] = (i < 3) ? clsb[i] : bb[i - 3];
    if (i < 1280) ghist[i] = 0;
}

// ---------------- kernel 2: MFMA fp16-split conv3x3+ReLU + 1x1 heads (r10, unchanged) ----------------
__global__ __launch_bounds__(512) void k_conv(
    FeatPtrs fp, const f16* __restrict__ whi, const f16* __restrict__ wlo,
    const float* __restrict__ convb, const float* __restrict__ headw,
    const float* __restrict__ headb, float* __restrict__ scores,
    float* __restrict__ deltas) {
    __shared__ float4 smq[4896];  // 78336 B: A hi/lo 2x6400 @0, B 2x32768 @12800
    char* smb = (char*)smq;
    const int tid = threadIdx.x;
    const int lane = tid & 63, wv = tid >> 6;
    const int l15 = lane & 15, l4 = lane >> 4;

    const int bid = blockIdx.x;
    int l = 0;
#pragma unroll
    for (int q = 1; q < 5; q++) if (bid >= cv_boff[q]) l = q;
    const int H = c_W[l], W = H;
    const int soff = c_soff[l];
    const float* __restrict__ in = fp.p[l];
    const int t = bid - cv_boff[l];
    const int tilesx = (W + 7) >> 3;
    const int tx = t % tilesx, ty = t / tilesx;
    const int x0 = tx * 8, y0 = ty * 8;
    const int HW = H * W;

    int rbase0, rbase1, rbase2, rbase3;
    {
        int rr = l15 >> 3;
        rbase0 = (0 + rr) * 640; rbase1 = (2 + rr) * 640;
        rbase2 = (4 + rr) * 640; rbase3 = (6 + rr) * 640;
    }
    int colx0, colx1, colx2;
    {
        int c = lane & 7;
        int p0 = c, p1 = c + 1, p2 = c + 2;
        colx0 = p0 * 64 + ((l4 ^ ((p0 >> 1) & 3)) << 4);
        colx1 = p1 * 64 + ((l4 ^ ((p1 >> 1) & 3)) << 4);
        colx2 = p2 * 64 + ((l4 ^ ((p2 >> 1) & 3)) << 4);
    }
    int bco0 = wv * 32 + l15, bco1 = wv * 32 + 16 + l15;
    const int boff0 = bco0 * 64 + ((l4 ^ ((bco0 >> 1) & 3)) << 4);
    const int boff1 = bco1 * 64 + ((l4 ^ ((bco1 >> 1) & 3)) << 4);

    f32x4 acc1[4][2], acc2[4][2];
#pragma unroll
    for (int mt = 0; mt < 4; mt++)
#pragma unroll
        for (int nt = 0; nt < 2; nt++) {
            acc1[mt][nt] = (f32x4)0.0f;
            acc2[mt][nt] = (f32x4)0.0f;
        }

    auto stagePatch = [&](int chunk) {
        const int c0 = chunk << 5;
        f16* ph = (f16*)smb;
        f16* pl = (f16*)(smb + 6400);
        for (int e = tid; e < 3200; e += 512) {
            int py = e / 320, rem = e - py * 320;
            int px = rem >> 5, ci = rem & 31;
            int gy = y0 - 1 + py, gx = x0 - 1 + px;
            float v = 0.f;
            if (gy >= 0 && gy < H && gx >= 0 && gx < W)
                v = in[(c0 + ci) * HW + gy * W + gx];
            f16 hi = (f16)v;
            int widx = py * 320 + px * 32 + (((ci >> 3) ^ ((px >> 1) & 3)) << 3) + (ci & 7);
            ph[widx] = hi;
            pl[widx] = (f16)((v - (float)hi) * 2048.0f);
        }
    };
    auto issueB = [&](int sidx, int buf) {
        const char* gh = (const char*)whi + (size_t)sidx * 16384;
        const char* gl = (const char*)wlo + (size_t)sidx * 16384;
        char* dh = smb + 12800 + buf * 32768;
        char* dl = dh + 16384;
#pragma unroll
        for (int q = 0; q < 2; q++) {
            int i1 = (wv * 2 + q) * 1024;
            __builtin_amdgcn_global_load_lds((gu32*)(gh + i1 + lane * 16), (lu32*)(dh + i1), 16, 0, 0);
            __builtin_amdgcn_global_load_lds((gu32*)(gl + i1 + lane * 16), (lu32*)(dl + i1), 16, 0, 0);
        }
    };

    stagePatch(0);
    issueB(0, 0);
    __syncthreads();

    for (int chunk = 0; chunk < 8; ++chunk) {
        if (chunk) { stagePatch(chunk); __syncthreads(); }
#pragma unroll
        for (int kk = 0; kk < 9; ++kk) {
            const int s = chunk * 9 + kk;
            const int buf = s & 1;
            if (s < 71) issueB(s + 1, buf ^ 1);
            {
                const int ky = kk / 3, kx = kk - ky * 3;
                const int kyb = ky * 640;
                const int cx = (kx == 0) ? colx0 : (kx == 1) ? colx1 : colx2;
                const char* bh = smb + 12800 + buf * 32768;
                const char* bl = bh + 16384;
                f16x8 ah0 = *(const f16x8*)(smb + rbase0 + kyb + cx);
                f16x8 ah1 = *(const f16x8*)(smb + rbase1 + kyb + cx);
                f16x8 ah2 = *(const f16x8*)(smb + rbase2 + kyb + cx);
                f16x8 ah3 = *(const f16x8*)(smb + rbase3 + kyb + cx);
                f16x8 al0 = *(const f16x8*)(smb + 6400 + rbase0 + kyb + cx);
                f16x8 al1 = *(const f16x8*)(smb + 6400 + rbase1 + kyb + cx);
                f16x8 al2 = *(const f16x8*)(smb + 6400 + rbase2 + kyb + cx);
                f16x8 al3 = *(const f16x8*)(smb + 6400 + rbase3 + kyb + cx);
#pragma unroll
                for (int nt = 0; nt < 2; nt++) {
                    const int bo = nt ? boff1 : boff0;
                    f16x8 vbh = *(const f16x8*)(bh + bo);
                    f16x8 vbl = *(const f16x8*)(bl + bo);
                    acc1[0][nt] = __builtin_amdgcn_mfma_f32_16x16x32_f16(ah0, vbh, acc1[0][nt], 0, 0, 0);
                    acc2[0][nt] = __builtin_amdgcn_mfma_f32_16x16x32_f16(ah0, vbl, acc2[0][nt], 0, 0, 0);
                    acc2[0][nt] = __builtin_amdgcn_mfma_f32_16x16x32_f16(al0, vbh, acc2[0][nt], 0, 0, 0);
                    acc1[1][nt] = __builtin_amdgcn_mfma_f32_16x16x32_f16(ah1, vbh, acc1[1][nt], 0, 0, 0);
                    acc2[1][nt] = __builtin_amdgcn_mfma_f32_16x16x32_f16(ah1, vbl, acc2[1][nt], 0, 0, 0);
                    acc2[1][nt] = __builtin_amdgcn_mfma_f32_16x16x32_f16(al1, vbh, acc2[1][nt], 0, 0, 0);
                    acc1[2][nt] = __builtin_amdgcn_mfma_f32_16x16x32_f16(ah2, vbh, acc1[2][nt], 0, 0, 0);
                    acc2[2][nt] = __builtin_amdgcn_mfma_f32_16x16x32_f16(ah2, vbl, acc2[2][nt], 0, 0, 0);
                    acc2[2][nt] = __builtin_amdgcn_mfma_f32_16x16x32_f16(al2, vbh, acc2[2][nt], 0, 0, 0);
                    acc1[3][nt] = __builtin_amdgcn_mfma_f32_16x16x32_f16(ah3, vbh, acc1[3][nt], 0, 0, 0);
                    acc2[3][nt] = __builtin_amdgcn_mfma_f32_16x16x32_f16(ah3, vbl, acc2[3][nt], 0, 0, 0);
                    acc2[3][nt] = __builtin_amdgcn_mfma_f32_16x16x32_f16(al3, vbh, acc2[3][nt], 0, 0, 0);
                }
            }
            __syncthreads();
        }
    }

    const float INV2048 = 4.8828125e-4f;
    {
        float cb0 = convb[bco0], cb1 = convb[bco1];
#pragma unroll
        for (int mt = 0; mt < 4; mt++)
#pragma unroll
            for (int nt = 0; nt < 2; nt++) {
                float cb = nt ? cb1 : cb0;
#pragma unroll
                for (int r = 0; r < 4; r++) {
                    float tv = acc1[mt][nt][r] + acc2[mt][nt][r] * INV2048 + cb;
                    acc1[mt][nt][r] = tv > 0.f ? tv : 0.f;
                }
            }
    }

    float* part = (float*)smb;  // [8 wv][64 px][3]
    for (int hc = 0; hc < 15; hc += 3) {
        float hw3[3][2];
#pragma unroll
        for (int h3 = 0; h3 < 3; h3++) {
            hw3[h3][0] = headw[(hc + h3) * 256 + bco0];
            hw3[h3][1] = headw[(hc + h3) * 256 + bco1];
        }
#pragma unroll
        for (int mt = 0; mt < 4; mt++)
#pragma unroll
            for (int r = 0; r < 4; r++) {
                float p0 = 0.f, p1 = 0.f, p2 = 0.f;
#pragma unroll
                for (int nt = 0; nt < 2; nt++) {
                    float tv = acc1[mt][nt][r];
                    p0 = fmaf(hw3[0][nt], tv, p0);
                    p1 = fmaf(hw3[1][nt], tv, p1);
                    p2 = fmaf(hw3[2][nt], tv, p2);
                }
                p0 += __shfl_xor(p0, 1); p0 += __shfl_xor(p0, 2); p0 += __shfl_xor(p0, 4); p0 += __shfl_xor(p0, 8);
                p1 += __shfl_xor(p1, 1); p1 += __shfl_xor(p1, 2); p1 += __shfl_xor(p1, 4); p1 += __shfl_xor(p1, 8);
                p2 += __shfl_xor(p2, 1); p2 += __shfl_xor(p2, 2); p2 += __shfl_xor(p2, 4); p2 += __shfl_xor(p2, 8);
                if (l15 == 0) {
                    int px = mt * 16 + l4 * 4 + r;
                    part[(wv * 64 + px) * 3 + 0] = p0;
                    part[(wv * 64 + px) * 3 + 1] = p1;
                    part[(wv * 64 + px) * 3 + 2] = p2;
                }
            }
        __syncthreads();
        if (tid < 192) {
            int px = tid / 3, h3 = tid % 3;
            int h = hc + h3;
            float sum = 0.f;
#pragma unroll
            for (int g = 0; g < 8; g++) sum += part[(g * 64 + px) * 3 + h3];
            sum += headb[h];
            int gy = y0 + (px >> 3), gx = x0 + (px & 7);
            if (gy < H && gx < W) {
                int pix = gy * W + gx;
                if (h < 3) {
                    scores[soff + pix * 3 + h] = sum;
                } else {
                    int ch2 = h - 3;
                    deltas[((size_t)(soff + pix * 3 + (ch2 >> 2))) * 4 + (ch2 & 3)] = sum;
                }
            }
        }
        __syncthreads();
    }
}

// ---------------- kernel 3a: chip-parallel byte-0 histogram (all levels) ----------------
__global__ __launch_bounds__(256) void k_hist(
    const float* __restrict__ scores, u32* __restrict__ ghist) {
    __shared__ u32 lh[1280];
    for (int i = threadIdx.x; i < 1280; i += 256) lh[i] = 0;
    __syncthreads();
    const int gsz = gridDim.x * 256;
    for (int i = blockIdx.x * 256 + threadIdx.x; i < TOTS; i += gsz) {
        int l = (i >= 120000) + (i >= 150000) + (i >= 157500) + (i >= 159375);
        u32 b = flipf(scores[i]) >> 24;
        atomicAdd(&lh[l * 256 + b], 1u);
    }
    __syncthreads();
    for (int i = threadIdx.x; i < 1280; i += 256) {
        u32 v = lh[i];
        if (v) atomicAdd(&ghist[i], v);
    }
}

// ---------------- kernel 3b: per-level exact top-k from precomputed byte-0 hist ----------------
// One classify scan (ballot-aggregated slot assignment: 1 atomic/wave, not /lane),
// then radix passes 1-3 on the COMPACTED tie list (mantissa bytes are uniform ->
// plain LDS atomics fine). Ties at full k32: m smallest indices via bitonic.
__global__ __launch_bounds__(1024) void k_topk2(
    const float* __restrict__ scores, const u32* __restrict__ ghist,
    u64* __restrict__ key, u64* __restrict__ scr1, u64* __restrict__ scr2) {
    const int l = blockIdx.x;
    const int Nl = c_Nl[l], off = c_soff[l], k = c_k[l];
    const int base = l * 1000;
    const int tid = threadIdx.x;
    const int lane = tid & 63;
    const u32 lshift = (u32)l << 24;
    __shared__ u32 hist[256];
    __shared__ u32 sh_sel, sh_cn, sh_b, sh_m;
    __shared__ u32 tiebuf[2048];

    if (k == Nl) {  // level 4: take everything, direct indexed write
        for (int i = tid; i < Nl; i += 1024) {
            u32 k32 = flipf(scores[off + i]);
            key[base + i] = ((u64)(~k32) << 32) | (u64)(lshift | (u32)i);
        }
        return;
    }
    if (tid == 0) {
        sh_sel = 0; sh_cn = 0;
        u32 cum = 0, m0 = (u32)k;
        for (int b = 255; b >= 0; --b) {
            u32 c = ghist[l * 256 + b];
            if (cum + c >= m0) { sh_b = (u32)b; sh_m = m0 - cum; break; }
            cum += c;
        }
    }
    __syncthreads();
    u32 b0 = sh_b, m = sh_m;

    // classify scan: > b0 -> emit final key; == b0 -> compact (k32<<32|idx) to scr1
    u64* C = scr1 + off;
    for (int i = tid; i < Nl; i += 1024) {
        u32 k32 = flipf(scores[off + i]);
        u32 b = k32 >> 24;
        bool sel = b > b0, tie = (b == b0);
        u64 msk = __ballot(sel);
        if (msk) {
            int ldr = __builtin_ctzll(msk);
            u32 bs = 0;
            if (lane == ldr) bs = atomicAdd(&sh_sel, (u32)__popcll(msk));
            bs = __shfl(bs, ldr);
            if (sel) {
                u32 slot = bs + (u32)__popcll(msk & ((1ull << lane) - 1ull));
                key[base + slot] = ((u64)(~k32) << 32) | (u64)(lshift | (u32)i);
            }
        }
        msk = __ballot(tie);
        if (msk) {
            int ldr = __builtin_ctzll(msk);
            u32 bs = 0;
            if (lane == ldr) bs = atomicAdd(&sh_cn, (u32)__popcll(msk));
            bs = __shfl(bs, ldr);
            if (tie) {
                u32 slot = bs + (u32)__popcll(msk & ((1ull << lane) - 1ull));
                C[slot] = ((u64)k32 << 32) | (u64)(u32)i;
            }
        }
    }
    __syncthreads();
    u32 n = sh_cn;
    __syncthreads();

    u64* curb = C;
    u64* nxtb = scr2 + off;
    for (int p = 1; p <= 3; ++p) {
        const int shift = 56 - 8 * p;  // byte p of k32 (stored in high 32 bits)
        for (int b = tid; b < 256; b += 1024) hist[b] = 0;
        if (tid == 0) sh_cn = 0;
        __syncthreads();
        for (u32 j = tid; j < n; j += 1024)
            atomicAdd(&hist[(u32)(curb[j] >> shift) & 255u], 1u);
        __syncthreads();
        if (tid == 0) {
            u32 cum = 0;
            for (int b = 255; b >= 0; --b) {
                u32 c = hist[b];
                if (cum + c >= m) { sh_b = (u32)b; sh_m = m - cum; break; }
                cum += c;
            }
        }
        __syncthreads();
        u32 bp = sh_b; m = sh_m;
        for (u32 j = tid; j < n; j += 1024) {
            u64 e = curb[j];
            u32 b = (u32)(e >> shift) & 255u;
            bool sel = b > bp, tie = (b == bp);
            u64 msk = __ballot(sel);
            if (msk) {
                int ldr = __builtin_ctzll(msk);
                u32 bs = 0;
                if (lane == ldr) bs = atomicAdd(&sh_sel, (u32)__popcll(msk));
                bs = __shfl(bs, ldr);
                if (sel) {
                    u32 slot = bs + (u32)__popcll(msk & ((1ull << lane) - 1ull));
                    u32 k32 = (u32)(e >> 32);
                    key[base + slot] = ((u64)(~k32) << 32) | (u64)(lshift | (u32)(e & 0xFFFFFFu));
                }
            }
            msk = __ballot(tie);
            if (msk) {
                int ldr = __builtin_ctzll(msk);
                u32 bs = 0;
                if (lane == ldr) bs = atomicAdd(&sh_cn, (u32)__popcll(msk));
                bs = __shfl(bs, ldr);
                if (tie) {
                    u32 slot = bs + (u32)__popcll(msk & ((1ull << lane) - 1ull));
                    nxtb[slot] = e;
                }
            }
        }
        __syncthreads();
        n = sh_cn;
        __syncthreads();
        u64* tmp = curb; curb = nxtb; nxtb = tmp;
    }

    // remaining: n entries, all with identical k32; need the m smallest indices
    u32 nsel = sh_sel;
    u32 kt = (u32)(curb[0] >> 32);  // n >= m >= 1
    if (n == m) {
        for (u32 j = tid; j < n; j += 1024) {
            u64 e = curb[j];
            key[base + nsel + j] = ((u64)(~kt) << 32) | (u64)(lshift | (u32)(e & 0xFFFFFFu));
        }
    } else {
        for (u32 j = tid; j < 2048; j += 1024) tiebuf[j] = 0xFFFFFFFFu;
        __syncthreads();
        for (u32 j = tid; j < n && j < 2048; j += 1024) tiebuf[j] = (u32)(curb[j] & 0xFFFFFFu);
        __syncthreads();
        for (u32 ksz = 2; ksz <= 2048; ksz <<= 1) {
            for (u32 jj = ksz >> 1; jj > 0; jj >>= 1) {
                for (u32 i2 = tid; i2 < 2048; i2 += 1024) {
                    u32 ixj = i2 ^ jj;
                    if (ixj > i2) {
                        u32 a = tiebuf[i2], b = tiebuf[ixj];
                        bool up = ((i2 & ksz) == 0);
                        if ((a > b) == up) { tiebuf[i2] = b; tiebuf[ixj] = a; }
                    }
                }
                __syncthreads();
            }
        }
        for (u32 j = tid; j < m; j += 1024)
            key[base + nsel + j] = ((u64)(~kt) << 32) | (u64)(lshift | tiebuf[j]);
    }
}

// ---------------- kernel 4: global bitonic sort + inline decode ----------------
__global__ __launch_bounds__(1024) void k_sort(
    const u64* __restrict__ key, const float* __restrict__ deltas, DecParams P,
    float* __restrict__ sboxes, float* __restrict__ sob, u32* __restrict__ svalid) {
    __shared__ u64 sk[8192];
    const int tid = threadIdx.x;
    for (int i = tid; i < 8192; i += 1024) sk[i] = (i < NCAND) ? key[i] : ~0ull;
    __syncthreads();
    for (u32 ksz = 2; ksz <= 8192; ksz <<= 1) {
        for (u32 j = ksz >> 1; j > 0; j >>= 1) {
            for (u32 i = tid; i < 8192; i += 1024) {
                u32 ixj = i ^ j;
                if (ixj > i) {
                    u64 a = sk[i], b = sk[ixj];
                    bool up = ((i & ksz) == 0);
                    if ((a > b) == up) { sk[i] = b; sk[ixj] = a; }
                }
            }
            __syncthreads();
        }
    }
    const float CLAMP = 4.135166556742356f;
    for (int s = tid; s < NCAND; s += 1024) {
        u32 info = (u32)sk[s];
        int l = info >> 24, idx = info & 0xFFFFFF;
        int W = c_W[l], st = c_stride[l];
        int a = idx % 3, pix = idx / 3;
        int x = pix % W, y = pix / W;
        float ax1 = x * st + P.b[l][a][0];
        float ay1 = y * st + P.b[l][a][1];
        float ax2 = x * st + P.b[l][a][2];
        float ay2 = y * st + P.b[l][a][3];
        float w_ = ax2 - ax1, h_ = ay2 - ay1;
        float cx = ax1 + 0.5f * w_, cy = ay1 + 0.5f * h_;
        const float* d = deltas + ((size_t)(c_soff[l] + idx)) * 4;
        float dx = d[0], dy = d[1];
        float dw = fminf(d[2], CLAMP), dh = fminf(d[3], CLAMP);
        float pcx = dx * w_ + cx, pcy = dy * h_ + cy;
        float pw = expf(dw) * w_, ph = expf(dh) * h_;
        float x1 = pcx - 0.5f * pw, y1 = pcy - 0.5f * ph;
        float x2 = pcx + 0.5f * pw, y2 = pcy + 0.5f * ph;
        x1 = fminf(fmaxf(x1, 0.f), 800.f); y1 = fminf(fmaxf(y1, 0.f), 800.f);
        x2 = fminf(fmaxf(x2, 0.f), 800.f); y2 = fminf(fmaxf(y2, 0.f), 800.f);
        u32 vv = (x2 - x1 >= 0.001f && y2 - y1 >= 0.001f) ? 1u : 0u;
        float offv = (float)l * 801.0f;
        sboxes[s * 4 + 0] = x1; sboxes[s * 4 + 1] = y1;
        sboxes[s * 4 + 2] = x2; sboxes[s * 4 + 3] = y2;
        sob[s * 4 + 0] = x1 + offv; sob[s * 4 + 1] = y1 + offv;
        sob[s * 4 + 2] = x2 + offv; sob[s * 4 + 3] = y2 + offv;
        svalid[s] = vv;
    }
}

// ---------------- kernel 5: IoU suppression bitmask ----------------
__global__ __launch_bounds__(256) void k_mask(
    const float* __restrict__ sob, u64* __restrict__ mask) {
    int gid = blockIdx.x * 256 + threadIdx.x;
    const int total = NCAND * WORDS;
    if (gid >= total) return;
    int i = gid / WORDS, w = gid - i * WORDS;
    float bx1 = sob[i * 4], by1 = sob[i * 4 + 1], bx2 = sob[i * 4 + 2], by2 = sob[i * 4 + 3];
    float ai = (bx2 - bx1) * (by2 - by1);
    u64 bits = 0;
    int j0 = w * 64;
    for (int b = 0; b < 64; b++) {
        int j = j0 + b;
        if (j < NCAND && j > i) {
            float cx1 = sob[j * 4], cy1 = sob[j * 4 + 1], cx2 = sob[j * 4 + 2], cy2 = sob[j * 4 + 3];
            float lt0 = fmaxf(bx1, cx1), lt1 = fmaxf(by1, cy1);
            float rb0 = fminf(bx2, cx2), rb1 = fminf(by2, cy2);
            float ww = fmaxf(rb0 - lt0, 0.f), hh = fmaxf(rb1 - lt1, 0.f);
            float inter = ww * hh;
            float aj = (cx2 - cx1) * (cy2 - cy1);
            float u = ai + aj - inter;
            float iou = inter / u;
            if (iou > 0.7f) bits |= (1ull << b);
        }
    }
    mask[(size_t)i * WORDS + w] = bits;
}

// ---------------- kernel 6: tiled greedy NMS scan + fused final gather ----------------
__global__ __launch_bounds__(1024) void k_scan(
    const u64* __restrict__ mask, const u32* __restrict__ svalid,
    const float* __restrict__ sboxes, float* __restrict__ out) {
    __shared__ u64 keep[WORDS];
    __shared__ u32 ormL[WORDS], ormH[WORDS];
    __shared__ u32 sc[1024];
    const int tid = threadIdx.x;
    if (tid < WORDS) {
        u64 w0 = 0;
        for (int b = 0; b < 64; b++) {
            int idx = tid * 64 + b;
            if (idx < NCAND && svalid[idx]) w0 |= (1ull << b);
        }
        keep[tid] = w0; ormL[tid] = 0; ormH[tid] = 0;
    }
    __syncthreads();
    for (int t = 0; t < WORDS; t++) {
        if (tid < 64) {
            int row = t * 64 + tid;
            u64 d = (row < NCAND) ? mask[(size_t)row * WORDS + t] : 0ull;
            u32 dlo = (u32)d, dhi = (u32)(d >> 32);
            u64 cur = keep[t];
            u64 pending = cur;
            while (pending) {
                int b = __builtin_ctzll(pending);
                pending &= pending - 1;
                u64 mb = ((u64)__shfl(dhi, b, 64) << 32) | (u64)__shfl(dlo, b, 64);
                cur &= ~mb;
                pending &= ~mb;
            }
            if (tid == 0) keep[t] = cur;
        }
        __syncthreads();
        u64 kw = keep[t];
        int nW = WORDS - 1 - t;
        for (int task = tid; task < 64 * nW; task += 1024) {
            int r = task / nW, w = t + 1 + (task - r * nW);
            if ((kw >> r) & 1ull) {
                u64 mrow = mask[(size_t)(t * 64 + r) * WORDS + w];
                if (mrow) {
                    atomicOr(&ormL[w], (u32)mrow);
                    atomicOr(&ormH[w], (u32)(mrow >> 32));
                }
            }
        }
        __syncthreads();
        if (tid > t && tid < WORDS) {
            keep[tid] &= ~(((u64)ormH[tid] << 32) | (u64)ormL[tid]);
            ormL[tid] = 0; ormH[tid] = 0;
        }
        __syncthreads();
    }
    // ---- fused gather (kept first, then suppressed in index order) ----
    const int i0 = tid * 5;
    u32 cnt = 0;
    for (int e = 0; e < 5; e++) {
        int i = i0 + e;
        if (i < NCAND) cnt += (u32)((keep[i >> 6] >> (i & 63)) & 1ull);
    }
    sc[tid] = cnt;
    __syncthreads();
    for (int off = 1; off < 1024; off <<= 1) {
        u32 v = (tid >= off) ? sc[tid - off] : 0;
        __syncthreads();
        sc[tid] += v;
        __syncthreads();
    }
    u32 incl = sc[tid];
    u32 total = sc[1023];
    u32 kr = incl - cnt;
    for (int e = 0; e < 5; e++) {
        int i = i0 + e;
        if (i < NCAND) {
            bool kp = (keep[i >> 6] >> (i & 63)) & 1ull;
            if (kp) {
                if (kr < 1000u) {
                    out[kr * 4 + 0] = sboxes[i * 4 + 0];
                    out[kr * 4 + 1] = sboxes[i * 4 + 1];
                    out[kr * 4 + 2] = sboxes[i * 4 + 2];
                    out[kr * 4 + 3] = sboxes[i * 4 + 3];
                }
                kr++;
            } else {
                u32 slot = total + (u32)i - kr;
                if (slot < 1000u) {
                    out[slot * 4 + 0] = sboxes[i * 4 + 0];
                    out[slot * 4 + 1] = sboxes[i * 4 + 1];
                    out[slot * 4 + 2] = sboxes[i * 4 + 2];
                    out[slot * 4 + 3] = sboxes[i * 4 + 3];
                }
            }
        }
    }
}

// ---------------- host ----------------
extern "C" void kernel_launch(void* const* d_in, const int* in_sizes, int n_in,
                              void* d_out, int out_size, void* d_ws, size_t ws_size,
                              hipStream_t stream) {
    (void)in_sizes; (void)n_in; (void)out_size; (void)ws_size;
    FeatPtrs fp;
    for (int i = 0; i < 5; i++) fp.p[i] = (const float*)d_in[i];
    const float* conv_w = (const float*)d_in[5];
    const float* conv_b = (const float*)d_in[6];
    const float* cls_w  = (const float*)d_in[7];
    const float* cls_b  = (const float*)d_in[8];
    const float* bbox_w = (const float*)d_in[9];
    const float* bbox_b = (const float*)d_in[10];

    char* ws = (char*)d_ws;
    f16*   whi    = (f16*)(ws + OFF_WHI);
    f16*   wlo    = (f16*)(ws + OFF_WLO);
    float* headw  = (float*)(ws + OFF_HEADW);
    float* headb  = (float*)(ws + OFF_HEADB);
    float* scores = (float*)(ws + OFF_SCORES);
    float* deltas = (float*)(ws + OFF_DELTAS);
    u64*   key    = (u64*)(ws + OFF_KEY);
    float* sboxes = (float*)(ws + OFF_SBOX);
    float* sob    = (float*)(ws + OFF_SOB);
    u32*   svalid = (u32*)(ws + OFF_SVAL);
    u64*   maskp  = (u64*)(ws + OFF_MASK);
    u32*   ghist  = (u32*)(ws + OFF_GHIST);
    u64*   scr1   = maskp;          // topk scratch (free before k_mask)
    u64*   scr2   = maskp + TOTS;

    k_prep<<<2304, 256, 0, stream>>>(conv_w, cls_w, cls_b, bbox_w, bbox_b,
                                     whi, wlo, headw, headb, ghist);

    k_conv<<<863, 512, 0, stream>>>(fp, whi, wlo, conv_b, headw, headb, scores, deltas);

    k_hist<<<256, 256, 0, stream>>>(scores, ghist);
    k_topk2<<<5, 1024, 0, stream>>>(scores, ghist, key, scr1, scr2);

    DecParams dp;
    {
        const double sz[5] = {32.0, 64.0, 128.0, 256.0, 512.0};
        const double rt[3] = {0.5, 1.0, 2.0};
        for (int l = 0; l < 5; l++)
            for (int a = 0; a < 3; a++) {
                double hr = sqrt(rt[a]);
                double wr = 1.0 / hr;
                double w = wr * sz[l], h = hr * sz[l];
                dp.b[l][a][0] = (float)nearbyint(-w / 2.0);
                dp.b[l][a][1] = (float)nearbyint(-h / 2.0);
                dp.b[l][a][2] = (float)nearbyint(w / 2.0);
                dp.b[l][a][3] = (float)nearbyint(h / 2.0);
            }
    }
    k_sort<<<1, 1024, 0, stream>>>(key, deltas, dp, sboxes, sob, svalid);
    k_mask<<<(NCAND * WORDS + 255) / 256, 256, 0, stream>>>(sob, maskp);
    k_scan<<<1, 1024, 0, stream>>>(maskp, svalid, sboxes, (float*)d_out);
}